// Round 3
// baseline (2042.600 us; speedup 1.0000x reference)
//
#include <hip/hip_runtime.h>
#include <hip/hip_bf16.h>

#define BF16 __hip_bfloat16

typedef short short8 __attribute__((ext_vector_type(8)));
typedef float v4f __attribute__((ext_vector_type(4)));
typedef float f4 __attribute__((ext_vector_type(4)));

__device__ __forceinline__ short f2bs(float f) {
    __hip_bfloat16 h = __float2bfloat16(f);
    return *(short*)&h;
}

// convert 8 contiguous fp32 (16B-aligned) to short8 of bf16 bits
__device__ __forceinline__ short8 cvt8(const float* __restrict__ p) {
    f4 a = *(const f4*)p;
    f4 b = *(const f4*)(p + 4);
    short8 r;
    r[0] = f2bs(a.x); r[1] = f2bs(a.y); r[2] = f2bs(a.z); r[3] = f2bs(a.w);
    r[4] = f2bs(b.x); r[5] = f2bs(b.y); r[6] = f2bs(b.z); r[7] = f2bs(b.w);
    return r;
}

// ---------------------------------------------------------------------------
// GEMM: C[M x Nr] = A[M x K] @ W[Nr x K]^T + bias.  A,W,bias,C all fp32 in
// global; A/W rounded to bf16 during LDS staging; fp32 MFMA accumulate.
// 128x128 tile, BK=32, 4 waves (2x2), each wave 64x64 via 4x4 mfma 16x16x32.
// Requires Kr % 8 == 0.
// ---------------------------------------------------------------------------
__global__ __launch_bounds__(256) void gemm_bt(
    const float* __restrict__ A, int lda,
    const float* __restrict__ W, int ldb,
    const float* __restrict__ bias,
    float* __restrict__ C, int ldc,
    int M, int Nr, int Kr)
{
    __shared__ __align__(16) BF16 As[128 * 40];   // +8 pad: bank-conflict dodge
    __shared__ __align__(16) BF16 Bs[128 * 40];

    const int tid  = threadIdx.x;
    const int lane = tid & 63;
    const int wave = tid >> 6;
    const int quad = lane >> 4;
    const int l16  = lane & 15;
    const int wm   = (wave >> 1) * 64;
    const int wn   = (wave & 1) * 64;
    const int m0   = blockIdx.y * 128;
    const int n0   = blockIdx.x * 128;

    const v4f zf = {0.f, 0.f, 0.f, 0.f};
    v4f acc[4][4];
#pragma unroll
    for (int i = 0; i < 4; ++i)
#pragma unroll
        for (int j = 0; j < 4; ++j) acc[i][j] = zf;

    const short8 zero8 = {0, 0, 0, 0, 0, 0, 0, 0};
    const int nk = (Kr + 31) >> 5;

    for (int kt = 0; kt < nk; ++kt) {
        const int k0 = kt << 5;
#pragma unroll
        for (int i = 0; i < 2; ++i) {
            int c  = tid + i * 256;        // 0..511 chunk id
            int r  = c >> 2;               // 0..127 row
            int kc = (c & 3) << 3;         // 0,8,16,24
            int gk = k0 + kc;
            int gm = m0 + r;
            short8 va = zero8;
            if (gm < M && gk < Kr)
                va = cvt8(A + (size_t)gm * lda + gk);
            *(short8*)(As + r * 40 + kc) = va;
            int gn = n0 + r;
            short8 vb = zero8;
            if (gn < Nr && gk < Kr)
                vb = cvt8(W + (size_t)gn * ldb + gk);
            *(short8*)(Bs + r * 40 + kc) = vb;
        }
        __syncthreads();

        short8 af[4], bfg[4];
#pragma unroll
        for (int mt = 0; mt < 4; ++mt)
            af[mt] = *(const short8*)(As + (wm + mt * 16 + l16) * 40 + quad * 8);
#pragma unroll
        for (int nt = 0; nt < 4; ++nt)
            bfg[nt] = *(const short8*)(Bs + (wn + nt * 16 + l16) * 40 + quad * 8);
#pragma unroll
        for (int mt = 0; mt < 4; ++mt)
#pragma unroll
            for (int nt = 0; nt < 4; ++nt)
                acc[mt][nt] = __builtin_amdgcn_mfma_f32_16x16x32_bf16(
                    af[mt], bfg[nt], acc[mt][nt], 0, 0, 0);
        __syncthreads();
    }

    // epilogue: D layout col(n)=lane&15, row(m)=quad*4+reg  [m89-verified]
#pragma unroll
    for (int nt = 0; nt < 4; ++nt) {
        int col = n0 + wn + nt * 16 + l16;
        if (col >= Nr) continue;
        float bvv = bias[col];
#pragma unroll
        for (int mt = 0; mt < 4; ++mt) {
#pragma unroll
            for (int r2 = 0; r2 < 4; ++r2) {
                int row = m0 + wm + mt * 16 + quad * 4 + r2;
                if (row < M)
                    C[(size_t)row * ldc + col] = acc[mt][nt][r2] + bvv;
            }
        }
    }
}

// ---------------------------------------------------------------------------
// Flash attention over the quirky head view: per (b,h), the Q/K/V head slice
// is the contiguous block base = b*N*D + h*N*96, row q at base + q*96
// (reshape(B,H,N,HD) of the flat [B,N,D] buffer -- NOT a transpose).
// Output merged standard way: O[b, q, h*96+hd], fp32.
// Q/K/V fp32 in global, rounded to bf16 at load; softmax + O accum fp32.
// One block = (b, h, 64-query tile); 4 waves, 16 queries each; key tiles of 32.
// ---------------------------------------------------------------------------
__global__ __launch_bounds__(256) void attn_flash(
    const float* __restrict__ Q, const float* __restrict__ K,
    const float* __restrict__ V, float* __restrict__ O)
{
    constexpr int NQ = 729, HDk = 96, DM = 1152;
    constexpr float NEG = -30000.f;               // finite mask (scores are O(1))
    __shared__ __align__(16) BF16 Ks[32 * 104];   // [32 keys][96 hd], stride 104
    __shared__ __align__(16) BF16 Vt[96 * 40];    // transposed [96 hd][32 keys]
    __shared__ __align__(16) BF16 Ps[4][16 * 40]; // per-wave P [16 q][32 keys]

    const int b = blockIdx.z, hh = blockIdx.y, qt = blockIdx.x;
    const int tid = threadIdx.x, wave = tid >> 6, lane = tid & 63;
    const int quad = lane >> 4, l16 = lane & 15;
    const size_t base = (size_t)b * (NQ * DM) + (size_t)hh * (NQ * HDk);

    const short8 zero8 = {0, 0, 0, 0, 0, 0, 0, 0};
    const v4f zf = {0.f, 0.f, 0.f, 0.f};

    // Q fragments (A-operand): row m = lane&15, k = quad*8+j  [m120-verified]
    const int qrow = qt * 64 + wave * 16 + l16;
    short8 aq[3];
#pragma unroll
    for (int ks = 0; ks < 3; ++ks)
        aq[ks] = (qrow < NQ)
            ? cvt8(Q + base + (size_t)qrow * HDk + ks * 32 + quad * 8)
            : zero8;

    v4f oacc[6];
#pragma unroll
    for (int i = 0; i < 6; ++i) oacc[i] = zf;
    float mrow[4] = {NEG, NEG, NEG, NEG};
    float lrow[4] = {0.f, 0.f, 0.f, 0.f};
    const float scale = 0.10206207261596577f;  // 96^-0.5

    for (int kt = 0; kt < 23; ++kt) {
        const int k0 = kt * 32;
        // stage K tile: 384 chunks of 8 elems
#pragma unroll
        for (int i = 0; i < 2; ++i) {
            int c = tid + i * 256;
            if (c < 384) {
                int r = c / 12, kc = (c % 12) * 8;
                int kg = k0 + r;
                short8 v = zero8;
                if (kg < NQ) v = cvt8(K + base + (size_t)kg * HDk + kc);
                *(short8*)(Ks + r * 104 + kc) = v;
            }
        }
        // stage V tile transposed: 3072 scalar elements
#pragma unroll
        for (int i = 0; i < 12; ++i) {
            int e  = tid + i * 256;
            int kr = e / 96, hd = e - kr * 96;
            int kg = k0 + kr;
            Vt[hd * 40 + kr] = (kg < NQ) ? __float2bfloat16(V[base + (size_t)kg * HDk + hd])
                                         : __float2bfloat16(0.f);
        }
        __syncthreads();

        // S = Q K^T : 16 queries x 32 keys (two 16x16 n-tiles, K-dim 96 = 3x32)
        v4f s0 = zf, s1 = zf;
#pragma unroll
        for (int ks = 0; ks < 3; ++ks) {
            short8 bk0 = *(const short8*)(Ks + l16 * 104 + ks * 32 + quad * 8);
            short8 bk1 = *(const short8*)(Ks + (16 + l16) * 104 + ks * 32 + quad * 8);
            s0 = __builtin_amdgcn_mfma_f32_16x16x32_bf16(aq[ks], bk0, s0, 0, 0, 0);
            s1 = __builtin_amdgcn_mfma_f32_16x16x32_bf16(aq[ks], bk1, s1, 0, 0, 0);
        }
        const int key0 = k0 + l16, key1 = k0 + 16 + l16;
        float sv0[4], sv1[4];
#pragma unroll
        for (int r = 0; r < 4; ++r) {
            sv0[r] = (key0 < NQ) ? s0[r] * scale : NEG;
            sv1[r] = (key1 < NQ) ? s1[r] * scale : NEG;
        }
        // row-wise max across the 16 lanes of this quad group
        float rmax[4];
#pragma unroll
        for (int r = 0; r < 4; ++r) rmax[r] = fmaxf(sv0[r], sv1[r]);
#pragma unroll
        for (int mm = 1; mm < 16; mm <<= 1)
#pragma unroll
            for (int r = 0; r < 4; ++r)
                rmax[r] = fmaxf(rmax[r], __shfl_xor(rmax[r], mm, 16));

        float alpha[4], p0[4], p1[4], rsum[4];
#pragma unroll
        for (int r = 0; r < 4; ++r) {
            float mnew = fmaxf(mrow[r], rmax[r]);
            alpha[r] = __expf(mrow[r] - mnew);
            mrow[r]  = mnew;
            p0[r] = __expf(sv0[r] - mnew);
            p1[r] = __expf(sv1[r] - mnew);
            rsum[r] = p0[r] + p1[r];
        }
#pragma unroll
        for (int mm = 1; mm < 16; mm <<= 1)
#pragma unroll
            for (int r = 0; r < 4; ++r)
                rsum[r] += __shfl_xor(rsum[r], mm, 16);
#pragma unroll
        for (int r = 0; r < 4; ++r) lrow[r] = lrow[r] * alpha[r] + rsum[r];

        // write P (C-layout) to per-wave LDS, re-read in A-layout
        BF16* Pw = &Ps[wave][0];
#pragma unroll
        for (int r = 0; r < 4; ++r) {
            Pw[(quad * 4 + r) * 40 + l16]      = __float2bfloat16(p0[r]);
            Pw[(quad * 4 + r) * 40 + 16 + l16] = __float2bfloat16(p1[r]);
        }
#pragma unroll
        for (int nt = 0; nt < 6; ++nt)
#pragma unroll
            for (int r = 0; r < 4; ++r) oacc[nt][r] *= alpha[r];
        __syncthreads();   // orders P write->read (LDS fence across the pun)

        short8 ap = *(const short8*)(Pw + l16 * 40 + quad * 8);
#pragma unroll
        for (int nt = 0; nt < 6; ++nt) {
            short8 bv = *(const short8*)(Vt + (nt * 16 + l16) * 40 + quad * 8);
            oacc[nt] = __builtin_amdgcn_mfma_f32_16x16x32_bf16(ap, bv, oacc[nt], 0, 0, 0);
        }
        __syncthreads();   // protect Ks/Vt before next staging
    }

    const int qb = qt * 64 + wave * 16 + quad * 4;
#pragma unroll
    for (int r = 0; r < 4; ++r) {
        int q = qb + r;
        if (q >= NQ) continue;
        float inv = (lrow[r] > 0.f) ? 1.f / lrow[r] : 0.f;
#pragma unroll
        for (int nt = 0; nt < 6; ++nt)
            O[(size_t)b * (NQ * DM) + (size_t)q * DM + hh * HDk + nt * 16 + l16] =
                oacc[nt][r] * inv;
    }
}

// ---------------------------------------------------------------------------
// LayerNorm helpers + fused kernels (all fp32)
// ---------------------------------------------------------------------------
__device__ __forceinline__ float block_sum256(float v, float* red, int tid)
{
#pragma unroll
    for (int mm = 1; mm < 64; mm <<= 1) v += __shfl_xor(v, mm, 64);
    if ((tid & 63) == 0) red[tid >> 6] = v;
    __syncthreads();
    float r = red[0] + red[1] + red[2] + red[3];
    __syncthreads();
    return r;
}

// h = LN(ao)*g + b + x ; g_out = gelu_tanh(h)
__global__ __launch_bounds__(256) void ln1_gelu_kernel(
    const float* __restrict__ ao, const float* __restrict__ x,
    const float* __restrict__ gw, const float* __restrict__ bw,
    float* __restrict__ hout, float* __restrict__ gout)
{
    __shared__ float red[4];
    const int row = blockIdx.x, tid = threadIdx.x;
    const float* ar = ao + (size_t)row * 1152;
    float vals[5];
    float s = 0.f;
#pragma unroll
    for (int j = 0; j < 5; ++j) {
        int idx = tid + j * 256;
        vals[j] = (idx < 1152) ? ar[idx] : 0.f;
        s += vals[j];
    }
    s = block_sum256(s, red, tid);
    float mu = s * (1.f / 1152.f);
    float vsum = 0.f;
#pragma unroll
    for (int j = 0; j < 5; ++j) {
        int idx = tid + j * 256;
        if (idx < 1152) { float d = vals[j] - mu; vsum += d * d; }
    }
    vsum = block_sum256(vsum, red, tid);
    float rstd = rsqrtf(vsum * (1.f / 1152.f) + 1e-6f);
#pragma unroll
    for (int j = 0; j < 5; ++j) {
        int idx = tid + j * 256;
        if (idx < 1152) {
            float hv = (vals[j] - mu) * rstd * gw[idx] + bw[idx]
                     + x[(size_t)row * 1152 + idx];
            hout[(size_t)row * 1152 + idx] = hv;
            float t = hv;
            float gl = 0.5f * t * (1.f + tanhf(0.7978845608028654f * (t + 0.044715f * t * t * t)));
            gout[(size_t)row * 1152 + idx] = gl;
        }
    }
}

// out = LN(m2)*g + b + h
__global__ __launch_bounds__(256) void ln2_kernel(
    const float* __restrict__ m2, const float* __restrict__ hf,
    const float* __restrict__ gw, const float* __restrict__ bw,
    float* __restrict__ out)
{
    __shared__ float red[4];
    const int row = blockIdx.x, tid = threadIdx.x;
    const float* mr = m2 + (size_t)row * 1152;
    float vals[5];
    float s = 0.f;
#pragma unroll
    for (int j = 0; j < 5; ++j) {
        int idx = tid + j * 256;
        vals[j] = (idx < 1152) ? mr[idx] : 0.f;
        s += vals[j];
    }
    s = block_sum256(s, red, tid);
    float mu = s * (1.f / 1152.f);
    float vsum = 0.f;
#pragma unroll
    for (int j = 0; j < 5; ++j) {
        int idx = tid + j * 256;
        if (idx < 1152) { float d = vals[j] - mu; vsum += d * d; }
    }
    vsum = block_sum256(vsum, red, tid);
    float rstd = rsqrtf(vsum * (1.f / 1152.f) + 1e-6f);
#pragma unroll
    for (int j = 0; j < 5; ++j) {
        int idx = tid + j * 256;
        if (idx < 1152) {
            out[(size_t)row * 1152 + idx] =
                (vals[j] - mu) * rstd * gw[idx] + bw[idx]
              + hf[(size_t)row * 1152 + idx];
        }
    }
}

// ---------------------------------------------------------------------------
// Workspace: 3 fp32 [T,D] slots = 80,621,568 bytes.
//   P0: Q -> attn_out -> M1 strips (1458x4304 fp32 = 25.1MB <= 26.9MB slot)
//   P1: K -> h
//   P2: V -> gelu(h) -> m2 (per-strip overwrite)
// Attention output stages through d_out (fp32 [T,D], overwritten by final LN).
// fc1/fc2 run in 4 row-strips of 1458 so M1 fits the P0 slot.
// ---------------------------------------------------------------------------
extern "C" void kernel_launch(void* const* d_in, const int* in_sizes, int n_in,
                              void* d_out, int out_size, void* d_ws, size_t ws_size,
                              hipStream_t stream)
{
    const float* x    = (const float*)d_in[0];
    const float* wq   = (const float*)d_in[1];
    const float* bq   = (const float*)d_in[2];
    const float* wk   = (const float*)d_in[3];
    const float* bk   = (const float*)d_in[4];
    const float* wv   = (const float*)d_in[5];
    const float* bv   = (const float*)d_in[6];
    const float* wo   = (const float*)d_in[7];
    const float* bo   = (const float*)d_in[8];
    const float* ln1g = (const float*)d_in[9];
    const float* ln1b = (const float*)d_in[10];
    const float* wfc1 = (const float*)d_in[11];
    const float* bfc1 = (const float*)d_in[12];
    const float* wfc2 = (const float*)d_in[13];
    const float* bfc2 = (const float*)d_in[14];
    const float* ln2g = (const float*)d_in[15];
    const float* ln2b = (const float*)d_in[16];

    const int T = 8 * 729;          // 5832 tokens
    const int D = 1152, HID = 4304;
    const size_t TD = (size_t)T * D;

    float* P0 = (float*)d_ws;
    float* P1 = P0 + TD;
    float* P2 = P1 + TD;
    float* Ob = (float*)d_out;

    dim3 blk(256);
    dim3 gD(9, 46);    // N=1152 -> 9 col tiles, M=5832 -> 46 row tiles

    gemm_bt<<<gD, blk, 0, stream>>>(x, D, wq, D, bq, P0, D, T, D, D);
    gemm_bt<<<gD, blk, 0, stream>>>(x, D, wk, D, bk, P1, D, T, D, D);
    gemm_bt<<<gD, blk, 0, stream>>>(x, D, wv, D, bv, P2, D, T, D, D);

    attn_flash<<<dim3(12, 12, 8), blk, 0, stream>>>(P0, P1, P2, Ob);

    gemm_bt<<<gD, blk, 0, stream>>>(Ob, D, wo, D, bo, P0, D, T, D, D);

    ln1_gelu_kernel<<<T, blk, 0, stream>>>(P0, x, ln1g, ln1b, P1, P2);

    // MLP in 4 row-strips of 1458 so M1 (fp32) fits in the P0 slot
    const int RS = 1458;
    dim3 gH_s(34, 12);   // fc1: N=4304 -> 34 tiles, M=1458 -> 12 tiles
    dim3 gD_s(9, 12);    // fc2: N=1152 -> 9 tiles
    for (int s = 0; s < 4; ++s) {
        const float* gs = P2 + (size_t)s * RS * D;
        float*       ms = P2 + (size_t)s * RS * D;
        gemm_bt<<<gH_s, blk, 0, stream>>>(gs, D, wfc1, D, bfc1, P0, HID, RS, HID, D);
        gemm_bt<<<gD_s, blk, 0, stream>>>(P0, HID, wfc2, HID, bfc2, ms, D, RS, D, HID);
    }

    ln2_kernel<<<T, blk, 0, stream>>>(P2, P1, ln2g, ln2b, (float*)d_out);
}

// Round 4
// 771.785 us; speedup vs baseline: 2.6466x; 2.6466x over previous
//
#include <hip/hip_runtime.h>
#include <hip/hip_bf16.h>

#define BF16 __hip_bfloat16

typedef short short8 __attribute__((ext_vector_type(8)));
typedef short short4v __attribute__((ext_vector_type(4)));
typedef float v4f __attribute__((ext_vector_type(4)));
typedef float f4 __attribute__((ext_vector_type(4)));

__device__ __forceinline__ short f2bs(float f) {
    __hip_bfloat16 h = __float2bfloat16(f);
    return *(short*)&h;
}

// async global->LDS 16B copy (lane i lands at ldst + i*16B; ldst wave-uniform)
__device__ __forceinline__ void async_cp16(const BF16* g, BF16* l) {
    __builtin_amdgcn_global_load_lds(
        (const __attribute__((address_space(1))) void*)g,
        (__attribute__((address_space(3))) void*)l,
        16, 0, 0);
}

// ---------------------------------------------------------------------------
// fp32 -> bf16 converters (one-shot per launch)
// ---------------------------------------------------------------------------
__global__ __launch_bounds__(256) void cvt4_kernel(
    const float* __restrict__ src, BF16* __restrict__ dst, int n4src, int n4dst)
{
    int i = blockIdx.x * 256 + threadIdx.x;
    if (i >= n4dst) return;
    short4v o = {0, 0, 0, 0};
    if (i < n4src) {
        f4 v = ((const f4*)src)[i];
        o[0] = f2bs(v.x); o[1] = f2bs(v.y); o[2] = f2bs(v.z); o[3] = f2bs(v.w);
    }
    ((short4v*)dst)[i] = o;
}

// wfc2 [1152][4304] fp32 -> [1152][4352] bf16, pad cols zero
__global__ __launch_bounds__(256) void cvt_padcols_kernel(
    const float* __restrict__ src, BF16* __restrict__ dst)
{
    int i = blockIdx.x * 256 + threadIdx.x;     // i < 1152*1088
    if (i >= 1152 * 1088) return;
    int row = i / 1088;
    int c = (i - row * 1088) * 4;
    short4v o = {0, 0, 0, 0};
    if (c < 4304) {
        f4 v = *(const f4*)(src + (size_t)row * 4304 + c);
        o[0] = f2bs(v.x); o[1] = f2bs(v.y); o[2] = f2bs(v.z); o[3] = f2bs(v.w);
    }
    *(short4v*)(dst + (size_t)row * 4352 + c) = o;
}

// ---------------------------------------------------------------------------
// m97-style GEMM: C[M x Nr] = A[M x K] @ W[Nr x K]^T + bias (fp32), bf16 io.
// 128x128 tile, BK=32, global_load_lds 16B staging, unpadded LDS stride 32.
// REQUIREMENTS: Nr == gridDim.x*128 exactly; Kr % 32 == 0; A may be read up
// to 127 rows past M (must be backed by adjacent ws memory); only the
// epilogue row-guards M.
// ---------------------------------------------------------------------------
__global__ __launch_bounds__(256) void gemm_bt_bf16(
    const BF16* __restrict__ A, int lda,
    const BF16* __restrict__ W, int ldb,
    const float* __restrict__ bias, int nbias,
    BF16* __restrict__ C, int ldc,
    int M, int Kr)
{
    __shared__ __align__(16) BF16 As[128 * 32];   // 8 KB, stride 32 (no pad:
    __shared__ __align__(16) BF16 Bs[128 * 32];   // global_load_lds needs it)

    const int tid  = threadIdx.x;
    const int lane = tid & 63;
    const int wave = tid >> 6;
    const int quad = lane >> 4;
    const int l16  = lane & 15;
    const int wm   = (wave >> 1) * 64;
    const int wn   = (wave & 1) * 64;
    const int m0   = blockIdx.y * 128;
    const int n0   = blockIdx.x * 128;

    const v4f zf = {0.f, 0.f, 0.f, 0.f};
    v4f acc[4][4];
#pragma unroll
    for (int i = 0; i < 4; ++i)
#pragma unroll
        for (int j = 0; j < 4; ++j) acc[i][j] = zf;

    // staging coords: chunk c in [0,512): row r=c>>2, k-col (c&3)*8
    const int c0 = tid, c1 = tid + 256;
    const int r0 = c0 >> 2, kc0 = (c0 & 3) << 3;
    const int r1 = c1 >> 2, kc1 = (c1 & 3) << 3;
    const BF16* ga0 = A + (size_t)(m0 + r0) * lda + kc0;
    const BF16* ga1 = A + (size_t)(m0 + r1) * lda + kc1;
    const BF16* gb0 = W + (size_t)(n0 + r0) * ldb + kc0;
    const BF16* gb1 = W + (size_t)(n0 + r1) * ldb + kc1;
    BF16* la0 = As + (c0 & ~63) * 8;   // wave-uniform LDS bases
    BF16* la1 = As + (c1 & ~63) * 8;
    BF16* lb0 = Bs + (c0 & ~63) * 8;
    BF16* lb1 = Bs + (c1 & ~63) * 8;

    const int nk = Kr >> 5;
    for (int kt = 0; kt < nk; ++kt) {
        async_cp16(ga0, la0);
        async_cp16(ga1, la1);
        async_cp16(gb0, lb0);
        async_cp16(gb1, lb1);
        ga0 += 32; ga1 += 32; gb0 += 32; gb1 += 32;
        __syncthreads();   // drains vmcnt (global_load_lds) before LDS reads

        short8 af[4], bfg[4];
#pragma unroll
        for (int mt = 0; mt < 4; ++mt)
            af[mt] = *(const short8*)(As + (wm + mt * 16 + l16) * 32 + quad * 8);
#pragma unroll
        for (int nt = 0; nt < 4; ++nt)
            bfg[nt] = *(const short8*)(Bs + (wn + nt * 16 + l16) * 32 + quad * 8);
#pragma unroll
        for (int mt = 0; mt < 4; ++mt)
#pragma unroll
            for (int nt = 0; nt < 4; ++nt)
                acc[mt][nt] = __builtin_amdgcn_mfma_f32_16x16x32_bf16(
                    af[mt], bfg[nt], acc[mt][nt], 0, 0, 0);
        __syncthreads();
    }

    // epilogue: D layout col(n)=lane&15, row(m)=quad*4+reg  [m89-verified]
#pragma unroll
    for (int nt = 0; nt < 4; ++nt) {
        int col = n0 + wn + nt * 16 + l16;
        float bvv = (col < nbias) ? bias[col] : 0.f;
#pragma unroll
        for (int mt = 0; mt < 4; ++mt) {
#pragma unroll
            for (int r2 = 0; r2 < 4; ++r2) {
                int row = m0 + wm + mt * 16 + quad * 4 + r2;
                if (row < M)
                    C[(size_t)row * ldc + col] = __float2bfloat16(acc[mt][nt][r2] + bvv);
            }
        }
    }
}

// ---------------------------------------------------------------------------
// Flash attention, bf16 io. Head view: per (b,h) the Q/K/V slice is the
// contiguous block base = b*N*D + h*N*96 (reshape, not transpose).
// Output merged: O[b, q, h*96+hd] bf16.
// One block = (b, h, 64-query tile); 4 waves, 16 queries each; key tiles 32.
// ---------------------------------------------------------------------------
__global__ __launch_bounds__(256) void attn_flash(
    const BF16* __restrict__ Q, const BF16* __restrict__ K,
    const BF16* __restrict__ V, BF16* __restrict__ O)
{
    constexpr int NQ = 729, HDk = 96, DM = 1152;
    constexpr float NEG = -30000.f;
    __shared__ __align__(16) BF16 Ks[32 * 104];
    __shared__ __align__(16) BF16 Vt[96 * 40];
    __shared__ __align__(16) BF16 Ps[4][16 * 40];

    const int b = blockIdx.z, hh = blockIdx.y, qt = blockIdx.x;
    const int tid = threadIdx.x, wave = tid >> 6, lane = tid & 63;
    const int quad = lane >> 4, l16 = lane & 15;
    const size_t base = (size_t)b * (NQ * DM) + (size_t)hh * (NQ * HDk);

    const short8 zero8 = {0, 0, 0, 0, 0, 0, 0, 0};
    const v4f zf = {0.f, 0.f, 0.f, 0.f};

    const int qrow = qt * 64 + wave * 16 + l16;
    short8 aq[3];
#pragma unroll
    for (int ks = 0; ks < 3; ++ks)
        aq[ks] = (qrow < NQ)
            ? *(const short8*)(Q + base + (size_t)qrow * HDk + ks * 32 + quad * 8)
            : zero8;

    v4f oacc[6];
#pragma unroll
    for (int i = 0; i < 6; ++i) oacc[i] = zf;
    float mrow[4] = {NEG, NEG, NEG, NEG};
    float lrow[4] = {0.f, 0.f, 0.f, 0.f};
    const float scale = 0.10206207261596577f;  // 96^-0.5

    for (int kt = 0; kt < 23; ++kt) {
        const int k0 = kt * 32;
#pragma unroll
        for (int i = 0; i < 2; ++i) {
            int c = tid + i * 256;
            if (c < 384) {
                int r = c / 12, kc = (c % 12) * 8;
                int kg = k0 + r;
                short8 v = zero8;
                if (kg < NQ) v = *(const short8*)(K + base + (size_t)kg * HDk + kc);
                *(short8*)(Ks + r * 104 + kc) = v;
            }
        }
#pragma unroll
        for (int i = 0; i < 12; ++i) {
            int e  = tid + i * 256;
            int kr = e / 96, hd = e - kr * 96;
            int kg = k0 + kr;
            Vt[hd * 40 + kr] = (kg < NQ) ? V[base + (size_t)kg * HDk + hd]
                                         : __float2bfloat16(0.f);
        }
        __syncthreads();

        v4f s0 = zf, s1 = zf;
#pragma unroll
        for (int ks = 0; ks < 3; ++ks) {
            short8 bk0 = *(const short8*)(Ks + l16 * 104 + ks * 32 + quad * 8);
            short8 bk1 = *(const short8*)(Ks + (16 + l16) * 104 + ks * 32 + quad * 8);
            s0 = __builtin_amdgcn_mfma_f32_16x16x32_bf16(aq[ks], bk0, s0, 0, 0, 0);
            s1 = __builtin_amdgcn_mfma_f32_16x16x32_bf16(aq[ks], bk1, s1, 0, 0, 0);
        }
        const int key0 = k0 + l16, key1 = k0 + 16 + l16;
        float sv0[4], sv1[4];
#pragma unroll
        for (int r = 0; r < 4; ++r) {
            sv0[r] = (key0 < NQ) ? s0[r] * scale : NEG;
            sv1[r] = (key1 < NQ) ? s1[r] * scale : NEG;
        }
        float rmax[4];
#pragma unroll
        for (int r = 0; r < 4; ++r) rmax[r] = fmaxf(sv0[r], sv1[r]);
#pragma unroll
        for (int mm = 1; mm < 16; mm <<= 1)
#pragma unroll
            for (int r = 0; r < 4; ++r)
                rmax[r] = fmaxf(rmax[r], __shfl_xor(rmax[r], mm, 16));

        float alpha[4], p0[4], p1[4], rsum[4];
#pragma unroll
        for (int r = 0; r < 4; ++r) {
            float mnew = fmaxf(mrow[r], rmax[r]);
            alpha[r] = __expf(mrow[r] - mnew);
            mrow[r]  = mnew;
            p0[r] = __expf(sv0[r] - mnew);
            p1[r] = __expf(sv1[r] - mnew);
            rsum[r] = p0[r] + p1[r];
        }
#pragma unroll
        for (int mm = 1; mm < 16; mm <<= 1)
#pragma unroll
            for (int r = 0; r < 4; ++r)
                rsum[r] += __shfl_xor(rsum[r], mm, 16);
#pragma unroll
        for (int r = 0; r < 4; ++r) lrow[r] = lrow[r] * alpha[r] + rsum[r];

        BF16* Pw = &Ps[wave][0];
#pragma unroll
        for (int r = 0; r < 4; ++r) {
            Pw[(quad * 4 + r) * 40 + l16]      = __float2bfloat16(p0[r]);
            Pw[(quad * 4 + r) * 40 + 16 + l16] = __float2bfloat16(p1[r]);
        }
#pragma unroll
        for (int nt = 0; nt < 6; ++nt)
#pragma unroll
            for (int r = 0; r < 4; ++r) oacc[nt][r] *= alpha[r];
        __syncthreads();

        short8 ap = *(const short8*)(Pw + l16 * 40 + quad * 8);
#pragma unroll
        for (int nt = 0; nt < 6; ++nt) {
            short8 bv = *(const short8*)(Vt + (nt * 16 + l16) * 40 + quad * 8);
            oacc[nt] = __builtin_amdgcn_mfma_f32_16x16x32_bf16(ap, bv, oacc[nt], 0, 0, 0);
        }
        __syncthreads();
    }

    const int qb = qt * 64 + wave * 16 + quad * 4;
#pragma unroll
    for (int r = 0; r < 4; ++r) {
        int q = qb + r;
        if (q >= NQ) continue;
        float inv = (lrow[r] > 0.f) ? 1.f / lrow[r] : 0.f;
#pragma unroll
        for (int nt = 0; nt < 6; ++nt)
            O[(size_t)b * (NQ * DM) + (size_t)q * DM + hh * HDk + nt * 16 + l16] =
                __float2bfloat16(oacc[nt][r] * inv);
    }
}

// ---------------------------------------------------------------------------
// LayerNorm fused kernels (bf16 io, fp32 math)
// ---------------------------------------------------------------------------
__device__ __forceinline__ float block_sum256(float v, float* red, int tid)
{
#pragma unroll
    for (int mm = 1; mm < 64; mm <<= 1) v += __shfl_xor(v, mm, 64);
    if ((tid & 63) == 0) red[tid >> 6] = v;
    __syncthreads();
    float r = red[0] + red[1] + red[2] + red[3];
    __syncthreads();
    return r;
}

// h = LN(ao)*g + b + x  -> hout (bf16); gelu_tanh(h) -> gout (bf16, may alias ao)
__global__ __launch_bounds__(256) void ln1_gelu_kernel(
    const BF16* __restrict__ ao, const float* __restrict__ x,
    const float* __restrict__ gw, const float* __restrict__ bw,
    BF16* __restrict__ hout, BF16* __restrict__ gout)
{
    __shared__ float red[4];
    const int row = blockIdx.x, tid = threadIdx.x;
    const BF16* ar = ao + (size_t)row * 1152;
    float vals[5];
    float s = 0.f;
#pragma unroll
    for (int j = 0; j < 5; ++j) {
        int idx = tid + j * 256;
        vals[j] = (idx < 1152) ? __bfloat162float(ar[idx]) : 0.f;
        s += vals[j];
    }
    s = block_sum256(s, red, tid);
    float mu = s * (1.f / 1152.f);
    float vsum = 0.f;
#pragma unroll
    for (int j = 0; j < 5; ++j) {
        int idx = tid + j * 256;
        if (idx < 1152) { float d = vals[j] - mu; vsum += d * d; }
    }
    vsum = block_sum256(vsum, red, tid);   // all reads of ao done before writes
    float rstd = rsqrtf(vsum * (1.f / 1152.f) + 1e-6f);
#pragma unroll
    for (int j = 0; j < 5; ++j) {
        int idx = tid + j * 256;
        if (idx < 1152) {
            float hv = (vals[j] - mu) * rstd * gw[idx] + bw[idx]
                     + x[(size_t)row * 1152 + idx];
            hout[(size_t)row * 1152 + idx] = __float2bfloat16(hv);
            float t = hv;
            float gl = 0.5f * t * (1.f + tanhf(0.7978845608028654f * (t + 0.044715f * t * t * t)));
            gout[(size_t)row * 1152 + idx] = __float2bfloat16(gl);
        }
    }
}

// out = LN(m2)*g + b + h   (out fp32 = d_out)
__global__ __launch_bounds__(256) void ln2_kernel(
    const BF16* __restrict__ m2, const BF16* __restrict__ hf,
    const float* __restrict__ gw, const float* __restrict__ bw,
    float* __restrict__ out)
{
    __shared__ float red[4];
    const int row = blockIdx.x, tid = threadIdx.x;
    const BF16* mr = m2 + (size_t)row * 1152;
    float vals[5];
    float s = 0.f;
#pragma unroll
    for (int j = 0; j < 5; ++j) {
        int idx = tid + j * 256;
        vals[j] = (idx < 1152) ? __bfloat162float(mr[idx]) : 0.f;
        s += vals[j];
    }
    s = block_sum256(s, red, tid);
    float mu = s * (1.f / 1152.f);
    float vsum = 0.f;
#pragma unroll
    for (int j = 0; j < 5; ++j) {
        int idx = tid + j * 256;
        if (idx < 1152) { float d = vals[j] - mu; vsum += d * d; }
    }
    vsum = block_sum256(vsum, red, tid);
    float rstd = rsqrtf(vsum * (1.f / 1152.f) + 1e-6f);
#pragma unroll
    for (int j = 0; j < 5; ++j) {
        int idx = tid + j * 256;
        if (idx < 1152) {
            out[(size_t)row * 1152 + idx] =
                (vals[j] - mu) * rstd * gw[idx] + bw[idx]
              + __bfloat162float(hf[(size_t)row * 1152 + idx]);
        }
    }
}

// ---------------------------------------------------------------------------
// Workspace layout (bf16 unless noted), ~125 MB total:
//   wbq wbk wbv wbo [1152*1152 each]
//   wbf1 [4352*1152] (rows 4304.. zero)   wbf2 [1152*4352] (cols 4304.. zero)
//   xb [T*1152]
//   S0..S3 [T*1152 each]: Q,K,V,AO; later M1 [T*4352] overlays S0..S3
//   C0 [T*1152]: attn_proj -> gelu(h) (in-place LN1) -> m2
//   C1 [T*1152]: h
//   64 KB slack (M-edge OOB staging reads land in-bounds)
// ---------------------------------------------------------------------------
extern "C" void kernel_launch(void* const* d_in, const int* in_sizes, int n_in,
                              void* d_out, int out_size, void* d_ws, size_t ws_size,
                              hipStream_t stream)
{
    const float* x    = (const float*)d_in[0];
    const float* wq   = (const float*)d_in[1];
    const float* bq   = (const float*)d_in[2];
    const float* wk   = (const float*)d_in[3];
    const float* bk   = (const float*)d_in[4];
    const float* wv   = (const float*)d_in[5];
    const float* bv   = (const float*)d_in[6];
    const float* wo   = (const float*)d_in[7];
    const float* bo   = (const float*)d_in[8];
    const float* ln1g = (const float*)d_in[9];
    const float* ln1b = (const float*)d_in[10];
    const float* wfc1 = (const float*)d_in[11];
    const float* bfc1 = (const float*)d_in[12];
    const float* wfc2 = (const float*)d_in[13];
    const float* bfc2 = (const float*)d_in[14];
    const float* ln2g = (const float*)d_in[15];
    const float* ln2b = (const float*)d_in[16];

    const int T = 8 * 729;           // 5832
    const int D = 1152, HIDP = 4352; // HID padded 4304 -> 4352 = 34*128
    const size_t TD = (size_t)T * D;
    const size_t WDD = (size_t)D * D;

    BF16* wbq  = (BF16*)d_ws;
    BF16* wbk  = wbq + WDD;
    BF16* wbv  = wbk + WDD;
    BF16* wbo  = wbv + WDD;
    BF16* wbf1 = wbo + WDD;                    // [4352*1152]
    BF16* wbf2 = wbf1 + (size_t)HIDP * D;      // [1152*4352]
    BF16* xb   = wbf2 + (size_t)D * HIDP;
    BF16* S0   = xb + TD;                      // Q ; M1 overlays S0..S3
    BF16* S1   = S0 + TD;                      // K
    BF16* S2   = S1 + TD;                      // V
    BF16* S3   = S2 + TD;                      // AO
    BF16* C0   = S3 + TD;                      // attn_proj -> gelu -> m2
    BF16* C1   = C0 + TD;                      // h
    BF16* M1   = S0;                           // [T*4352] <= 4*TD  OK

    dim3 blk(256);

    // --- one-shot converts ---
    const int n4_dd = (int)(WDD / 4);
    cvt4_kernel<<<(n4_dd + 255) / 256, blk, 0, stream>>>(wq, wbq, n4_dd, n4_dd);
    cvt4_kernel<<<(n4_dd + 255) / 256, blk, 0, stream>>>(wk, wbk, n4_dd, n4_dd);
    cvt4_kernel<<<(n4_dd + 255) / 256, blk, 0, stream>>>(wv, wbv, n4_dd, n4_dd);
    cvt4_kernel<<<(n4_dd + 255) / 256, blk, 0, stream>>>(wo, wbo, n4_dd, n4_dd);
    const int n4_f1s = 4304 * 1152 / 4, n4_f1d = HIDP * 1152 / 4;
    cvt4_kernel<<<(n4_f1d + 255) / 256, blk, 0, stream>>>(wfc1, wbf1, n4_f1s, n4_f1d);
    cvt_padcols_kernel<<<(1152 * 1088 + 255) / 256, blk, 0, stream>>>(wfc2, wbf2);
    const int n4_x = (int)(TD / 4);
    cvt4_kernel<<<(n4_x + 255) / 256, blk, 0, stream>>>(x, xb, n4_x, n4_x);

    // --- QKV projections ---
    dim3 gD(9, 46);
    gemm_bt_bf16<<<gD, blk, 0, stream>>>(xb, D, wbq, D, bq, D, S0, D, T, D);
    gemm_bt_bf16<<<gD, blk, 0, stream>>>(xb, D, wbk, D, bk, D, S1, D, T, D);
    gemm_bt_bf16<<<gD, blk, 0, stream>>>(xb, D, wbv, D, bv, D, S2, D, T, D);

    // --- attention ---
    attn_flash<<<dim3(12, 12, 8), blk, 0, stream>>>(S0, S1, S2, S3);

    // --- output projection ---
    gemm_bt_bf16<<<gD, blk, 0, stream>>>(S3, D, wbo, D, bo, D, C0, D, T, D);

    // --- LN1 + residual + gelu (gelu in-place over C0) ---
    ln1_gelu_kernel<<<T, blk, 0, stream>>>(C0, x, ln1g, ln1b, C1, C0);

    // --- MLP (full-size, padded HID) ---
    dim3 gH(34, 46);
    gemm_bt_bf16<<<gH, blk, 0, stream>>>(C0, D, wbf1, D, bfc1, 4304, M1, HIDP, T, D);
    gemm_bt_bf16<<<gD, blk, 0, stream>>>(M1, HIDP, wbf2, HIDP, bfc2, D, C0, D, T, HIDP);

    // --- LN2 + residual -> d_out (fp32) ---
    ln2_kernel<<<T, blk, 0, stream>>>(C0, C1, ln2g, ln2b, (float*)d_out);
}

// Round 5
// 698.840 us; speedup vs baseline: 2.9228x; 1.1044x over previous
//
#include <hip/hip_runtime.h>
#include <hip/hip_bf16.h>

#define BF16 __hip_bfloat16

typedef short short8 __attribute__((ext_vector_type(8)));
typedef short short4v __attribute__((ext_vector_type(4)));
typedef float v4f __attribute__((ext_vector_type(4)));
typedef float f4 __attribute__((ext_vector_type(4)));

__device__ __forceinline__ short f2bs(float f) {
    __hip_bfloat16 h = __float2bfloat16(f);
    return *(short*)&h;
}

// async global->LDS 16B copy (LDS dest: wave-uniform base + lane*16B)
__device__ __forceinline__ void async_cp16(const BF16* g, BF16* l) {
    __builtin_amdgcn_global_load_lds(
        (const __attribute__((address_space(1))) void*)g,
        (__attribute__((address_space(3))) void*)l,
        16, 0, 0);
}

// ---------------------------------------------------------------------------
// fp32 -> bf16 converters (one-shot per launch)
// ---------------------------------------------------------------------------
__global__ __launch_bounds__(256) void cvt4_kernel(
    const float* __restrict__ src, BF16* __restrict__ dst, int n4src, int n4dst)
{
    int i = blockIdx.x * 256 + threadIdx.x;
    if (i >= n4dst) return;
    short4v o = {0, 0, 0, 0};
    if (i < n4src) {
        f4 v = ((const f4*)src)[i];
        o[0] = f2bs(v.x); o[1] = f2bs(v.y); o[2] = f2bs(v.z); o[3] = f2bs(v.w);
    }
    ((short4v*)dst)[i] = o;
}

// wfc2 [1152][4304] fp32 -> [1152][4352] bf16, pad cols zero
__global__ __launch_bounds__(256) void cvt_padcols_kernel(
    const float* __restrict__ src, BF16* __restrict__ dst)
{
    int i = blockIdx.x * 256 + threadIdx.x;     // i < 1152*1088
    if (i >= 1152 * 1088) return;
    int row = i / 1088;
    int c = (i - row * 1088) * 4;
    short4v o = {0, 0, 0, 0};
    if (c < 4304) {
        f4 v = *(const f4*)(src + (size_t)row * 4304 + c);
        o[0] = f2bs(v.x); o[1] = f2bs(v.y); o[2] = f2bs(v.z); o[3] = f2bs(v.w);
    }
    *(short4v*)(dst + (size_t)row * 4352 + c) = o;
}

// ---------------------------------------------------------------------------
// V transpose: per head hg=(b,h), VT[hg][hd][kk] = V[b, kk, h*96+hd] view,
// kk padded 729->736 with zeros. Source reads L2-cached (140 KB/head).
// ---------------------------------------------------------------------------
__global__ __launch_bounds__(256) void transpose_v(
    const BF16* __restrict__ V, BF16* __restrict__ VT)
{
    const int hg = blockIdx.x;           // 0..95
    const int s  = blockIdx.y;           // 0..3  (24 hd rows each)
    const int b = hg / 12, hh = hg - b * 12;
    const BF16* src = V + (size_t)b * (729 * 1152) + (size_t)hh * (729 * 96);
    BF16* dst = VT + (size_t)hg * 96 * 736;
    const BF16 z = __float2bfloat16(0.f);
    for (int hd = s * 24; hd < s * 24 + 24; ++hd)
        for (int kk = threadIdx.x; kk < 736; kk += 256)
            dst[(size_t)hd * 736 + kk] = (kk < 729) ? src[(size_t)kk * 96 + hd] : z;
}

// ---------------------------------------------------------------------------
// m97-style GEMM: C[M x Nr] = A[M x K] @ W[Nr x K]^T + bias (fp32), bf16 io.
// 128x128 tile, BK=32, global_load_lds 16B staging, unpadded LDS stride 32.
// Nr == gridDim.x*128 exactly; Kr % 32 == 0; A may be read up to 127 rows
// past M (backed by adjacent ws memory); epilogue row-guards M.
// ---------------------------------------------------------------------------
__global__ __launch_bounds__(256) void gemm_bt_bf16(
    const BF16* __restrict__ A, int lda,
    const BF16* __restrict__ W, int ldb,
    const float* __restrict__ bias, int nbias,
    BF16* __restrict__ C, int ldc,
    int M, int Kr)
{
    __shared__ __align__(16) BF16 As[128 * 32];
    __shared__ __align__(16) BF16 Bs[128 * 32];

    const int tid  = threadIdx.x;
    const int lane = tid & 63;
    const int wave = tid >> 6;
    const int quad = lane >> 4;
    const int l16  = lane & 15;
    const int wm   = (wave >> 1) * 64;
    const int wn   = (wave & 1) * 64;
    const int m0   = blockIdx.y * 128;
    const int n0   = blockIdx.x * 128;

    const v4f zf = {0.f, 0.f, 0.f, 0.f};
    v4f acc[4][4];
#pragma unroll
    for (int i = 0; i < 4; ++i)
#pragma unroll
        for (int j = 0; j < 4; ++j) acc[i][j] = zf;

    const int c0 = tid, c1 = tid + 256;
    const int r0 = c0 >> 2, kc0 = (c0 & 3) << 3;
    const int r1 = c1 >> 2, kc1 = (c1 & 3) << 3;
    const BF16* ga0 = A + (size_t)(m0 + r0) * lda + kc0;
    const BF16* ga1 = A + (size_t)(m0 + r1) * lda + kc1;
    const BF16* gb0 = W + (size_t)(n0 + r0) * ldb + kc0;
    const BF16* gb1 = W + (size_t)(n0 + r1) * ldb + kc1;
    BF16* la0 = As + (c0 & ~63) * 8;
    BF16* la1 = As + (c1 & ~63) * 8;
    BF16* lb0 = Bs + (c0 & ~63) * 8;
    BF16* lb1 = Bs + (c1 & ~63) * 8;

    const int nk = Kr >> 5;
    for (int kt = 0; kt < nk; ++kt) {
        async_cp16(ga0, la0);
        async_cp16(ga1, la1);
        async_cp16(gb0, lb0);
        async_cp16(gb1, lb1);
        ga0 += 32; ga1 += 32; gb0 += 32; gb1 += 32;
        __syncthreads();

        short8 af[4], bfg[4];
#pragma unroll
        for (int mt = 0; mt < 4; ++mt)
            af[mt] = *(const short8*)(As + (wm + mt * 16 + l16) * 32 + quad * 8);
#pragma unroll
        for (int nt = 0; nt < 4; ++nt)
            bfg[nt] = *(const short8*)(Bs + (wn + nt * 16 + l16) * 32 + quad * 8);
#pragma unroll
        for (int mt = 0; mt < 4; ++mt)
#pragma unroll
            for (int nt = 0; nt < 4; ++nt)
                acc[mt][nt] = __builtin_amdgcn_mfma_f32_16x16x32_bf16(
                    af[mt], bfg[nt], acc[mt][nt], 0, 0, 0);
        __syncthreads();
    }

#pragma unroll
    for (int nt = 0; nt < 4; ++nt) {
        int col = n0 + wn + nt * 16 + l16;
        float bvv = (col < nbias) ? bias[col] : 0.f;
#pragma unroll
        for (int mt = 0; mt < 4; ++mt) {
#pragma unroll
            for (int r2 = 0; r2 < 4; ++r2) {
                int row = m0 + wm + mt * 16 + quad * 4 + r2;
                if (row < M)
                    C[(size_t)row * ldc + col] = __float2bfloat16(acc[mt][nt][r2] + bvv);
            }
        }
    }
}

// ---------------------------------------------------------------------------
// Fused QKV GEMM: W = stacked [3456][1152] (wq|wk|wv rows), output routed to
// three [T,1152] buffers C + sel*cstride, sel = n0/1152 (uniform per block).
// ---------------------------------------------------------------------------
__global__ __launch_bounds__(256) void gemm_qkv(
    const BF16* __restrict__ A,
    const BF16* __restrict__ W,
    const float* __restrict__ b0, const float* __restrict__ b1,
    const float* __restrict__ b2,
    BF16* __restrict__ C, size_t cstride, int M)
{
    __shared__ __align__(16) BF16 As[128 * 32];
    __shared__ __align__(16) BF16 Bs[128 * 32];

    const int tid  = threadIdx.x;
    const int lane = tid & 63;
    const int wave = tid >> 6;
    const int quad = lane >> 4;
    const int l16  = lane & 15;
    const int wm   = (wave >> 1) * 64;
    const int wn   = (wave & 1) * 64;
    const int m0   = blockIdx.y * 128;
    const int n0   = blockIdx.x * 128;

    const v4f zf = {0.f, 0.f, 0.f, 0.f};
    v4f acc[4][4];
#pragma unroll
    for (int i = 0; i < 4; ++i)
#pragma unroll
        for (int j = 0; j < 4; ++j) acc[i][j] = zf;

    const int c0 = tid, c1 = tid + 256;
    const int r0 = c0 >> 2, kc0 = (c0 & 3) << 3;
    const int r1 = c1 >> 2, kc1 = (c1 & 3) << 3;
    const BF16* ga0 = A + (size_t)(m0 + r0) * 1152 + kc0;
    const BF16* ga1 = A + (size_t)(m0 + r1) * 1152 + kc1;
    const BF16* gb0 = W + (size_t)(n0 + r0) * 1152 + kc0;
    const BF16* gb1 = W + (size_t)(n0 + r1) * 1152 + kc1;
    BF16* la0 = As + (c0 & ~63) * 8;
    BF16* la1 = As + (c1 & ~63) * 8;
    BF16* lb0 = Bs + (c0 & ~63) * 8;
    BF16* lb1 = Bs + (c1 & ~63) * 8;

    for (int kt = 0; kt < 36; ++kt) {
        async_cp16(ga0, la0);
        async_cp16(ga1, la1);
        async_cp16(gb0, lb0);
        async_cp16(gb1, lb1);
        ga0 += 32; ga1 += 32; gb0 += 32; gb1 += 32;
        __syncthreads();

        short8 af[4], bfg[4];
#pragma unroll
        for (int mt = 0; mt < 4; ++mt)
            af[mt] = *(const short8*)(As + (wm + mt * 16 + l16) * 32 + quad * 8);
#pragma unroll
        for (int nt = 0; nt < 4; ++nt)
            bfg[nt] = *(const short8*)(Bs + (wn + nt * 16 + l16) * 32 + quad * 8);
#pragma unroll
        for (int mt = 0; mt < 4; ++mt)
#pragma unroll
            for (int nt = 0; nt < 4; ++nt)
                acc[mt][nt] = __builtin_amdgcn_mfma_f32_16x16x32_bf16(
                    af[mt], bfg[nt], acc[mt][nt], 0, 0, 0);
        __syncthreads();
    }

    const int sel = n0 / 1152;                   // uniform per block
    const float* bp = (sel == 0) ? b0 : (sel == 1) ? b1 : b2;
    BF16* Cb = C + (size_t)sel * cstride;
    const int nl0 = n0 - sel * 1152;
#pragma unroll
    for (int nt = 0; nt < 4; ++nt) {
        int col = nl0 + wn + nt * 16 + l16;
        float bvv = bp[col];
#pragma unroll
        for (int mt = 0; mt < 4; ++mt) {
#pragma unroll
            for (int r2 = 0; r2 < 4; ++r2) {
                int row = m0 + wm + mt * 16 + quad * 4 + r2;
                if (row < M)
                    Cb[(size_t)row * 1152 + col] = __float2bfloat16(acc[mt][nt][r2] + bvv);
            }
        }
    }
}

// ---------------------------------------------------------------------------
// Flash attention v2: q-tile 128/block (4 waves x 32 queries), key tiles 32,
// K and pre-transposed V staged via global_load_lds, XCD-swizzled grid so all
// 6 q-tiles of one head share one XCD's L2.
// ---------------------------------------------------------------------------
__global__ __launch_bounds__(256) void attn_flash2(
    const BF16* __restrict__ Q, const BF16* __restrict__ K,
    const BF16* __restrict__ VT, BF16* __restrict__ O)
{
    constexpr int NQ = 729, HDk = 96, DM = 1152, LDV = 736;
    constexpr float NEG = -30000.f;
    __shared__ __align__(16) BF16 Ks[32 * 96];     // [32 keys][96 hd]
    __shared__ __align__(16) BF16 Vs[96 * 32];     // [96 hd][32 keys]
    __shared__ __align__(16) BF16 Ps[4][32 * 32];  // per-wave P [32 q][32 k]

    const int id = blockIdx.x;                 // 576 blocks
    const int xcd = id & 7, slot = id >> 3;    // slot 0..71
    const int hb = slot / 6, qt = slot - hb * 6;
    const int hg = xcd * 12 + hb;              // head 0..95, 12 heads per XCD
    const int b = hg / 12, hh = hg - b * 12;

    const int tid = threadIdx.x, wave = tid >> 6, lane = tid & 63;
    const int quad = lane >> 4, l16 = lane & 15;
    const size_t kbase = (size_t)b * (NQ * DM) + (size_t)hh * (NQ * HDk);
    const size_t vbase = (size_t)hg * 96 * LDV;

    // staging coords (K: 384 chunks [row=c/12, kc=(c%12)*8]; V: [hd=c/4, kc=(c&3)*8])
    const int ckr0 = tid / 12,         ckc0 = (tid - ckr0 * 12) * 8;
    const int c1   = tid + 256;
    const int ckr1 = c1 / 12,          ckc1 = (c1 - ckr1 * 12) * 8;
    const int vr0  = tid >> 2,         vc0  = (tid & 3) * 8;
    const int vr1  = c1 >> 2;
    const BF16* gk0 = K + kbase + (size_t)ckr0 * HDk + ckc0;
    const BF16* gk1 = K + kbase + (size_t)ckr1 * HDk + ckc1;
    const BF16* gv0 = VT + vbase + (size_t)vr0 * LDV + vc0;
    const BF16* gv1 = VT + vbase + (size_t)vr1 * LDV + vc0;
    BF16* lk0 = Ks + (tid & ~63) * 8;
    BF16* lk1 = Ks + (c1 & ~63) * 8;
    BF16* lv0 = Vs + (tid & ~63) * 8;
    BF16* lv1 = Vs + (c1 & ~63) * 8;

    const short8 zero8 = {0, 0, 0, 0, 0, 0, 0, 0};
    const v4f zf = {0.f, 0.f, 0.f, 0.f};
    const float scale = 0.10206207261596577f;  // 96^-0.5

    // Q fragments: 2 m-tiles x 3 k-slices, loaded once
    const int q0w = qt * 128 + wave * 32;
    short8 aq[2][3];
#pragma unroll
    for (int mt = 0; mt < 2; ++mt) {
        int qrow = q0w + mt * 16 + l16;
#pragma unroll
        for (int ks = 0; ks < 3; ++ks)
            aq[mt][ks] = (qrow < NQ)
                ? *(const short8*)(Q + kbase + (size_t)qrow * HDk + ks * 32 + quad * 8)
                : zero8;
    }

    v4f oacc[2][6];
#pragma unroll
    for (int mt = 0; mt < 2; ++mt)
#pragma unroll
        for (int nt = 0; nt < 6; ++nt) oacc[mt][nt] = zf;
    float mrow[2][4], lrow[2][4];
#pragma unroll
    for (int mt = 0; mt < 2; ++mt)
#pragma unroll
        for (int r = 0; r < 4; ++r) { mrow[mt][r] = NEG; lrow[mt][r] = 0.f; }

    for (int kt = 0; kt < 23; ++kt) {
        async_cp16(gk0, lk0);
        async_cp16(gv0, lv0);
        if (tid < 128) {
            async_cp16(gk1, lk1);
            async_cp16(gv1, lv1);
        }
        gk0 += 32 * HDk; gk1 += 32 * HDk; gv0 += 32; gv1 += 32;
        __syncthreads();   // drains async copies

        // S = Q K^T : per wave 32q x 32k
        v4f s[2][2];
        s[0][0] = zf; s[0][1] = zf; s[1][0] = zf; s[1][1] = zf;
#pragma unroll
        for (int ks = 0; ks < 3; ++ks) {
            short8 bk0 = *(const short8*)(Ks + l16 * 96 + ks * 32 + quad * 8);
            short8 bk1 = *(const short8*)(Ks + (16 + l16) * 96 + ks * 32 + quad * 8);
#pragma unroll
            for (int mt = 0; mt < 2; ++mt) {
                s[mt][0] = __builtin_amdgcn_mfma_f32_16x16x32_bf16(aq[mt][ks], bk0, s[mt][0], 0, 0, 0);
                s[mt][1] = __builtin_amdgcn_mfma_f32_16x16x32_bf16(aq[mt][ks], bk1, s[mt][1], 0, 0, 0);
            }
        }
        const int k0 = kt * 32;
        const int key0 = k0 + l16, key1 = k0 + 16 + l16;
        BF16* Pw = &Ps[wave][0];
#pragma unroll
        for (int mt = 0; mt < 2; ++mt) {
            float sv0[4], sv1[4], rmx[4], alpha[4], rsum[4], p0[4], p1[4];
#pragma unroll
            for (int r = 0; r < 4; ++r) {
                sv0[r] = (key0 < NQ) ? s[mt][0][r] * scale : NEG;
                sv1[r] = (key1 < NQ) ? s[mt][1][r] * scale : NEG;
                rmx[r] = fmaxf(sv0[r], sv1[r]);
            }
#pragma unroll
            for (int mm = 1; mm < 16; mm <<= 1)
#pragma unroll
                for (int r = 0; r < 4; ++r)
                    rmx[r] = fmaxf(rmx[r], __shfl_xor(rmx[r], mm, 16));
#pragma unroll
            for (int r = 0; r < 4; ++r) {
                float mnew = fmaxf(mrow[mt][r], rmx[r]);
                alpha[r] = __expf(mrow[mt][r] - mnew);
                mrow[mt][r] = mnew;
                p0[r] = __expf(sv0[r] - mnew);
                p1[r] = __expf(sv1[r] - mnew);
                rsum[r] = p0[r] + p1[r];
            }
#pragma unroll
            for (int mm = 1; mm < 16; mm <<= 1)
#pragma unroll
                for (int r = 0; r < 4; ++r)
                    rsum[r] += __shfl_xor(rsum[r], mm, 16);
#pragma unroll
            for (int r = 0; r < 4; ++r) {
                lrow[mt][r] = lrow[mt][r] * alpha[r] + rsum[r];
                Pw[(mt * 16 + quad * 4 + r) * 32 + l16]      = __float2bfloat16(p0[r]);
                Pw[(mt * 16 + quad * 4 + r) * 32 + 16 + l16] = __float2bfloat16(p1[r]);
            }
#pragma unroll
            for (int nt = 0; nt < 6; ++nt)
#pragma unroll
                for (int r = 0; r < 4; ++r) oacc[mt][nt][r] *= alpha[r];
        }
        __syncthreads();   // P write -> read ordering

        short8 ap0 = *(const short8*)(Pw + l16 * 32 + quad * 8);
        short8 ap1 = *(const short8*)(Pw + (16 + l16) * 32 + quad * 8);
#pragma unroll
        for (int nt = 0; nt < 6; ++nt) {
            short8 bv = *(const short8*)(Vs + (nt * 16 + l16) * 32 + quad * 8);
            oacc[0][nt] = __builtin_amdgcn_mfma_f32_16x16x32_bf16(ap0, bv, oacc[0][nt], 0, 0, 0);
            oacc[1][nt] = __builtin_amdgcn_mfma_f32_16x16x32_bf16(ap1, bv, oacc[1][nt], 0, 0, 0);
        }
        __syncthreads();   // protect Ks/Vs/Ps before next staging
    }

#pragma unroll
    for (int mt = 0; mt < 2; ++mt) {
        const int qb = q0w + mt * 16 + quad * 4;
#pragma unroll
        for (int r = 0; r < 4; ++r) {
            int q = qb + r;
            if (q >= NQ) continue;
            float inv = (lrow[mt][r] > 0.f) ? 1.f / lrow[mt][r] : 0.f;
#pragma unroll
            for (int nt = 0; nt < 6; ++nt)
                O[(size_t)b * (NQ * DM) + (size_t)q * DM + hh * HDk + nt * 16 + l16] =
                    __float2bfloat16(oacc[mt][nt][r] * inv);
        }
    }
}

// ---------------------------------------------------------------------------
// LayerNorm fused kernels (bf16 io, fp32 math)
// ---------------------------------------------------------------------------
__device__ __forceinline__ float block_sum256(float v, float* red, int tid)
{
#pragma unroll
    for (int mm = 1; mm < 64; mm <<= 1) v += __shfl_xor(v, mm, 64);
    if ((tid & 63) == 0) red[tid >> 6] = v;
    __syncthreads();
    float r = red[0] + red[1] + red[2] + red[3];
    __syncthreads();
    return r;
}

__global__ __launch_bounds__(256) void ln1_gelu_kernel(
    const BF16* __restrict__ ao, const float* __restrict__ x,
    const float* __restrict__ gw, const float* __restrict__ bw,
    BF16* __restrict__ hout, BF16* __restrict__ gout)
{
    __shared__ float red[4];
    const int row = blockIdx.x, tid = threadIdx.x;
    const BF16* ar = ao + (size_t)row * 1152;
    float vals[5];
    float s = 0.f;
#pragma unroll
    for (int j = 0; j < 5; ++j) {
        int idx = tid + j * 256;
        vals[j] = (idx < 1152) ? __bfloat162float(ar[idx]) : 0.f;
        s += vals[j];
    }
    s = block_sum256(s, red, tid);
    float mu = s * (1.f / 1152.f);
    float vsum = 0.f;
#pragma unroll
    for (int j = 0; j < 5; ++j) {
        int idx = tid + j * 256;
        if (idx < 1152) { float d = vals[j] - mu; vsum += d * d; }
    }
    vsum = block_sum256(vsum, red, tid);
    float rstd = rsqrtf(vsum * (1.f / 1152.f) + 1e-6f);
#pragma unroll
    for (int j = 0; j < 5; ++j) {
        int idx = tid + j * 256;
        if (idx < 1152) {
            float hv = (vals[j] - mu) * rstd * gw[idx] + bw[idx]
                     + x[(size_t)row * 1152 + idx];
            hout[(size_t)row * 1152 + idx] = __float2bfloat16(hv);
            float t = hv;
            float gl = 0.5f * t * (1.f + tanhf(0.7978845608028654f * (t + 0.044715f * t * t * t)));
            gout[(size_t)row * 1152 + idx] = __float2bfloat16(gl);
        }
    }
}

__global__ __launch_bounds__(256) void ln2_kernel(
    const BF16* __restrict__ m2, const BF16* __restrict__ hf,
    const float* __restrict__ gw, const float* __restrict__ bw,
    float* __restrict__ out)
{
    __shared__ float red[4];
    const int row = blockIdx.x, tid = threadIdx.x;
    const BF16* mr = m2 + (size_t)row * 1152;
    float vals[5];
    float s = 0.f;
#pragma unroll
    for (int j = 0; j < 5; ++j) {
        int idx = tid + j * 256;
        vals[j] = (idx < 1152) ? __bfloat162float(mr[idx]) : 0.f;
        s += vals[j];
    }
    s = block_sum256(s, red, tid);
    float mu = s * (1.f / 1152.f);
    float vsum = 0.f;
#pragma unroll
    for (int j = 0; j < 5; ++j) {
        int idx = tid + j * 256;
        if (idx < 1152) { float d = vals[j] - mu; vsum += d * d; }
    }
    vsum = block_sum256(vsum, red, tid);
    float rstd = rsqrtf(vsum * (1.f / 1152.f) + 1e-6f);
#pragma unroll
    for (int j = 0; j < 5; ++j) {
        int idx = tid + j * 256;
        if (idx < 1152) {
            out[(size_t)row * 1152 + idx] =
                (vals[j] - mu) * rstd * gw[idx] + bw[idx]
              + __bfloat162float(hf[(size_t)row * 1152 + idx]);
        }
    }
}

// ---------------------------------------------------------------------------
// Workspace (bf16), ~125 MB:
//   wbq|wbk|wbv (stacked QKV weight) wbo, wbf1 [4352x1152], wbf2 [1152x4352],
//   xb [T,1152], S0..S3 (Q,K,V,AO; M1 [T,4352] overlays), C0,C1.
//   VT [96][96][736] overlays C0 (dead before wo-GEMM writes C0).
// ---------------------------------------------------------------------------
extern "C" void kernel_launch(void* const* d_in, const int* in_sizes, int n_in,
                              void* d_out, int out_size, void* d_ws, size_t ws_size,
                              hipStream_t stream)
{
    const float* x    = (const float*)d_in[0];
    const float* wq   = (const float*)d_in[1];
    const float* bq   = (const float*)d_in[2];
    const float* wk   = (const float*)d_in[3];
    const float* bk   = (const float*)d_in[4];
    const float* wv   = (const float*)d_in[5];
    const float* bv   = (const float*)d_in[6];
    const float* wo   = (const float*)d_in[7];
    const float* bo   = (const float*)d_in[8];
    const float* ln1g = (const float*)d_in[9];
    const float* ln1b = (const float*)d_in[10];
    const float* wfc1 = (const float*)d_in[11];
    const float* bfc1 = (const float*)d_in[12];
    const float* wfc2 = (const float*)d_in[13];
    const float* bfc2 = (const float*)d_in[14];
    const float* ln2g = (const float*)d_in[15];
    const float* ln2b = (const float*)d_in[16];

    const int T = 8 * 729;           // 5832
    const int D = 1152, HIDP = 4352;
    const size_t TD = (size_t)T * D;
    const size_t WDD = (size_t)D * D;

    BF16* wbq  = (BF16*)d_ws;                  // stacked QKV: wbq,wbk,wbv
    BF16* wbk  = wbq + WDD;
    BF16* wbv  = wbk + WDD;
    BF16* wbo  = wbv + WDD;
    BF16* wbf1 = wbo + WDD;
    BF16* wbf2 = wbf1 + (size_t)HIDP * D;
    BF16* xb   = wbf2 + (size_t)D * HIDP;
    BF16* S0   = xb + TD;
    BF16* S1   = S0 + TD;
    BF16* S2   = S1 + TD;
    BF16* S3   = S2 + TD;
    BF16* C0   = S3 + TD;
    BF16* C1   = C0 + TD;
    BF16* M1   = S0;                           // [T*4352] overlays S0..S3
    BF16* VT   = C0;                           // [96*96*736] overlays C0(+C1 head)

    dim3 blk(256);

    // one-shot converts
    const int n4_dd = (int)(WDD / 4);
    cvt4_kernel<<<(n4_dd + 255) / 256, blk, 0, stream>>>(wq, wbq, n4_dd, n4_dd);
    cvt4_kernel<<<(n4_dd + 255) / 256, blk, 0, stream>>>(wk, wbk, n4_dd, n4_dd);
    cvt4_kernel<<<(n4_dd + 255) / 256, blk, 0, stream>>>(wv, wbv, n4_dd, n4_dd);
    cvt4_kernel<<<(n4_dd + 255) / 256, blk, 0, stream>>>(wo, wbo, n4_dd, n4_dd);
    const int n4_f1s = 4304 * 1152 / 4, n4_f1d = HIDP * 1152 / 4;
    cvt4_kernel<<<(n4_f1d + 255) / 256, blk, 0, stream>>>(wfc1, wbf1, n4_f1s, n4_f1d);
    cvt_padcols_kernel<<<(1152 * 1088 + 255) / 256, blk, 0, stream>>>(wfc2, wbf2);
    const int n4_x = (int)(TD / 4);
    cvt4_kernel<<<(n4_x + 255) / 256, blk, 0, stream>>>(x, xb, n4_x, n4_x);

    // fused QKV projection (grid 27x46 = 1242 blocks)
    gemm_qkv<<<dim3(27, 46), blk, 0, stream>>>(xb, wbq, bq, bk, bv, S0, TD, T);

    // V transpose + attention
    transpose_v<<<dim3(96, 4), blk, 0, stream>>>(S2, VT);
    attn_flash2<<<576, blk, 0, stream>>>(S0, S1, VT, S3);

    // output projection (VT dead; C0 reused)
    dim3 gD(9, 46);
    gemm_bt_bf16<<<gD, blk, 0, stream>>>(S3, D, wbo, D, bo, D, C0, D, T, D);

    // LN1 + residual + gelu (gelu in-place over C0)
    ln1_gelu_kernel<<<T, blk, 0, stream>>>(C0, x, ln1g, ln1b, C1, C0);

    // MLP
    dim3 gH(34, 46);
    gemm_bt_bf16<<<gH, blk, 0, stream>>>(C0, D, wbf1, D, bfc1, 4304, M1, HIDP, T, D);
    gemm_bt_bf16<<<gD, blk, 0, stream>>>(M1, HIDP, wbf2, HIDP, bfc2, D, C0, D, T, HIDP);

    // LN2 + residual -> d_out (fp32)
    ln2_kernel<<<T, blk, 0, stream>>>(C0, C1, ln2g, ln2b, (float*)d_out);
}

// Round 6
// 624.934 us; speedup vs baseline: 3.2685x; 1.1183x over previous
//
#include <hip/hip_runtime.h>
#include <hip/hip_bf16.h>

#define BF16 __hip_bfloat16

typedef short short8 __attribute__((ext_vector_type(8)));
typedef short short4v __attribute__((ext_vector_type(4)));
typedef float v4f __attribute__((ext_vector_type(4)));
typedef float f4 __attribute__((ext_vector_type(4)));

__device__ __forceinline__ short f2bs(float f) {
    __hip_bfloat16 h = __float2bfloat16(f);
    return *(short*)&h;
}

// async global->LDS 16B copy (LDS dest: wave-uniform base + lane*16B)
__device__ __forceinline__ void async_cp16(const BF16* g, BF16* l) {
    __builtin_amdgcn_global_load_lds(
        (const __attribute__((address_space(1))) void*)g,
        (__attribute__((address_space(3))) void*)l,
        16, 0, 0);
}

// ---------------------------------------------------------------------------
// fp32 -> bf16 converters (one-shot per launch)
// ---------------------------------------------------------------------------
__global__ __launch_bounds__(256) void cvt4_kernel(
    const float* __restrict__ src, BF16* __restrict__ dst, int n4src, int n4dst)
{
    int i = blockIdx.x * 256 + threadIdx.x;
    if (i >= n4dst) return;
    short4v o = {0, 0, 0, 0};
    if (i < n4src) {
        f4 v = ((const f4*)src)[i];
        o[0] = f2bs(v.x); o[1] = f2bs(v.y); o[2] = f2bs(v.z); o[3] = f2bs(v.w);
    }
    ((short4v*)dst)[i] = o;
}

// wfc2 [1152][4304] fp32 -> [1152][4352] bf16, pad cols zero
__global__ __launch_bounds__(256) void cvt_padcols_kernel(
    const float* __restrict__ src, BF16* __restrict__ dst)
{
    int i = blockIdx.x * 256 + threadIdx.x;     // i < 1152*1088
    if (i >= 1152 * 1088) return;
    int row = i / 1088;
    int c = (i - row * 1088) * 4;
    short4v o = {0, 0, 0, 0};
    if (c < 4304) {
        f4 v = *(const f4*)(src + (size_t)row * 4304 + c);
        o[0] = f2bs(v.x); o[1] = f2bs(v.y); o[2] = f2bs(v.z); o[3] = f2bs(v.w);
    }
    *(short4v*)(dst + (size_t)row * 4352 + c) = o;
}

// ---------------------------------------------------------------------------
// V transpose: per head hg=(b,h), VT[hg][hd][kk] = head-view V, kk padded
// 729->736 with zeros.
// ---------------------------------------------------------------------------
__global__ __launch_bounds__(256) void transpose_v(
    const BF16* __restrict__ V, BF16* __restrict__ VT)
{
    const int hg = blockIdx.x;           // 0..95
    const int s  = blockIdx.y;           // 0..3
    const int b = hg / 12, hh = hg - b * 12;
    const BF16* src = V + (size_t)b * (729 * 1152) + (size_t)hh * (729 * 96);
    BF16* dst = VT + (size_t)hg * 96 * 736;
    const BF16 z = __float2bfloat16(0.f);
    for (int hd = s * 24; hd < s * 24 + 24; ++hd)
        for (int kk = threadIdx.x; kk < 736; kk += 256)
            dst[(size_t)hd * 736 + kk] = (kk < 729) ? src[(size_t)kk * 96 + hd] : z;
}

// ---------------------------------------------------------------------------
// GEMM (templated m-tile): C[M x Nr] = A @ W^T + bias. bf16 io, fp32 acc.
// TM x 128 tile, BK=32, global_load_lds 16B staging with XOR-swizzled source
// groups (bank-conflict-free ds_read_b128), coalesced LDS-staged epilogue.
// Grid: blockIdx.x = m-tile (fast, pad to x8 for XCD residency),
//       blockIdx.y = n-tile (slow -> W-tile resident in per-XCD L2).
// Nr == gridDim.y*128 exactly; Kr % 32 == 0; A rows may be read up to
// TM-1 past M (must be backed by adjacent ws memory).
// Swizzle: source group g of row r stored at LDS group (g+((r>>1)&3))&3;
// reader at l16 lanes then spreads 16 rows over 8 bank-quads x2 (free).
// ---------------------------------------------------------------------------
template<int TM>
__global__ __launch_bounds__(256) void gemm_bt_t(
    const BF16* __restrict__ A, int lda,
    const BF16* __restrict__ W, int ldb,
    const float* __restrict__ bias, int nbias,
    BF16* __restrict__ C, int ldc,
    int M, int Kr)
{
    constexpr int MT = TM / 32;
    __shared__ __align__(16) BF16 smem[TM * 128];  // staging (TM+128)*32 fits
    BF16* As = smem;
    BF16* Bs = smem + TM * 32;

    const int tid  = threadIdx.x;
    const int lane = tid & 63;
    const int wave = tid >> 6;
    const int quad = lane >> 4;
    const int l16  = lane & 15;
    const int wm   = (wave >> 1) * (TM / 2);
    const int wn   = (wave & 1) * 64;
    const int m0   = blockIdx.x * TM;
    const int n0   = blockIdx.y * 128;
    if (m0 >= M) return;   // dead pad block (uniform)

    const v4f zf = {0.f, 0.f, 0.f, 0.f};
    v4f acc[MT][4];
#pragma unroll
    for (int i = 0; i < MT; ++i)
#pragma unroll
        for (int j = 0; j < 4; ++j) acc[i][j] = zf;

    // staging source coords; chunk c: row=c>>2, LDS-slot group c&3,
    // source group = ((c&3) - ((c>>3)&3)) & 3   (swizzle inverse)
    const int cA0 = tid;
    const int cB0 = tid, cB1 = tid + 256;
    const BF16* gA0 = A + (size_t)(m0 + (cA0 >> 2)) * lda + ((((cA0 & 3) - ((cA0 >> 3) & 3)) & 3) << 3);
    const BF16* gB0 = W + (size_t)(n0 + (cB0 >> 2)) * ldb + ((((cB0 & 3) - ((cB0 >> 3) & 3)) & 3) << 3);
    const BF16* gB1 = W + (size_t)(n0 + (cB1 >> 2)) * ldb + ((((cB1 & 3) - ((cB1 >> 3) & 3)) & 3) << 3);
    BF16* lA0 = As + (cA0 & ~63) * 8;
    BF16* lB0 = Bs + (cB0 & ~63) * 8;
    BF16* lB1 = Bs + (cB1 & ~63) * 8;
    const BF16* gA1 = nullptr; BF16* lA1 = nullptr;
    if constexpr (TM == 128) {
        const int cA1 = tid + 256;
        gA1 = A + (size_t)(m0 + (cA1 >> 2)) * lda + ((((cA1 & 3) - ((cA1 >> 3) & 3)) & 3) << 3);
        lA1 = As + (cA1 & ~63) * 8;
    }

    const int gsw = (l16 >> 1) & 3;   // reader swizzle: (row>>1)&3 == (l16>>1)&3
    const int nk = Kr >> 5;
    for (int kt = 0; kt < nk; ++kt) {
        async_cp16(gA0, lA0);
        if constexpr (TM == 128) async_cp16(gA1, lA1);
        async_cp16(gB0, lB0);
        async_cp16(gB1, lB1);
        gA0 += 32; gB0 += 32; gB1 += 32;
        if constexpr (TM == 128) gA1 += 32;
        __syncthreads();

        short8 af[MT], bfg[4];
#pragma unroll
        for (int mt = 0; mt < MT; ++mt) {
            int row = wm + mt * 16 + l16;
            af[mt] = *(const short8*)(As + row * 32 + (((quad + gsw) & 3) << 3));
        }
#pragma unroll
        for (int nt = 0; nt < 4; ++nt) {
            int row = wn + nt * 16 + l16;
            bfg[nt] = *(const short8*)(Bs + row * 32 + (((quad + gsw) & 3) << 3));
        }
#pragma unroll
        for (int mt = 0; mt < MT; ++mt)
#pragma unroll
            for (int nt = 0; nt < 4; ++nt)
                acc[mt][nt] = __builtin_amdgcn_mfma_f32_16x16x32_bf16(
                    af[mt], bfg[nt], acc[mt][nt], 0, 0, 0);
        __syncthreads();
    }

    // ---- coalesced epilogue: C-tile -> LDS (bf16+bias) -> short8 stores ----
    float bv[4];
#pragma unroll
    for (int nt = 0; nt < 4; ++nt) {
        int col = n0 + wn + nt * 16 + l16;
        bv[nt] = (col < nbias) ? bias[col] : 0.f;
    }
#pragma unroll
    for (int mt = 0; mt < MT; ++mt)
#pragma unroll
        for (int nt = 0; nt < 4; ++nt)
#pragma unroll
            for (int r2 = 0; r2 < 4; ++r2) {
                int row_l = wm + mt * 16 + quad * 4 + r2;
                int col_l = wn + nt * 16 + l16;
                smem[row_l * 128 + col_l] = __float2bfloat16(acc[mt][nt][r2] + bv[nt]);
            }
    __syncthreads();
#pragma unroll
    for (int p = 0; p < TM / 16; ++p) {
        int idx = p * 256 + tid;
        int row = m0 + (idx >> 4);
        if (row < M)
            *(short8*)(C + (size_t)row * ldc + n0 + (idx & 15) * 8) =
                *(const short8*)(smem + idx * 8);
    }
}

// ---------------------------------------------------------------------------
// Fused QKV GEMM (TM=128): W stacked [3456][1152]; output routed to three
// [T,1152] buffers by sel = n0/1152. Same swizzle + coalesced epilogue.
// ---------------------------------------------------------------------------
__global__ __launch_bounds__(256) void gemm_qkv(
    const BF16* __restrict__ A,
    const BF16* __restrict__ W,
    const float* __restrict__ b0, const float* __restrict__ b1,
    const float* __restrict__ b2,
    BF16* __restrict__ C, size_t cstride, int M)
{
    __shared__ __align__(16) BF16 smem[128 * 128];
    BF16* As = smem;
    BF16* Bs = smem + 128 * 32;

    const int tid  = threadIdx.x;
    const int lane = tid & 63;
    const int wave = tid >> 6;
    const int quad = lane >> 4;
    const int l16  = lane & 15;
    const int wm   = (wave >> 1) * 64;
    const int wn   = (wave & 1) * 64;
    const int m0   = blockIdx.x * 128;
    const int n0   = blockIdx.y * 128;
    if (m0 >= M) return;

    const v4f zf = {0.f, 0.f, 0.f, 0.f};
    v4f acc[4][4];
#pragma unroll
    for (int i = 0; i < 4; ++i)
#pragma unroll
        for (int j = 0; j < 4; ++j) acc[i][j] = zf;

    const int cA0 = tid, cA1 = tid + 256;
    const BF16* gA0 = A + (size_t)(m0 + (cA0 >> 2)) * 1152 + ((((cA0 & 3) - ((cA0 >> 3) & 3)) & 3) << 3);
    const BF16* gA1 = A + (size_t)(m0 + (cA1 >> 2)) * 1152 + ((((cA1 & 3) - ((cA1 >> 3) & 3)) & 3) << 3);
    const BF16* gB0 = W + (size_t)(n0 + (cA0 >> 2)) * 1152 + ((((cA0 & 3) - ((cA0 >> 3) & 3)) & 3) << 3);
    const BF16* gB1 = W + (size_t)(n0 + (cA1 >> 2)) * 1152 + ((((cA1 & 3) - ((cA1 >> 3) & 3)) & 3) << 3);
    BF16* lA0 = As + (cA0 & ~63) * 8;
    BF16* lA1 = As + (cA1 & ~63) * 8;
    BF16* lB0 = Bs + (cA0 & ~63) * 8;
    BF16* lB1 = Bs + (cA1 & ~63) * 8;

    const int gsw = (l16 >> 1) & 3;
    for (int kt = 0; kt < 36; ++kt) {
        async_cp16(gA0, lA0);
        async_cp16(gA1, lA1);
        async_cp16(gB0, lB0);
        async_cp16(gB1, lB1);
        gA0 += 32; gA1 += 32; gB0 += 32; gB1 += 32;
        __syncthreads();

        short8 af[4], bfg[4];
#pragma unroll
        for (int mt = 0; mt < 4; ++mt) {
            int row = wm + mt * 16 + l16;
            af[mt] = *(const short8*)(As + row * 32 + (((quad + gsw) & 3) << 3));
        }
#pragma unroll
        for (int nt = 0; nt < 4; ++nt) {
            int row = wn + nt * 16 + l16;
            bfg[nt] = *(const short8*)(Bs + row * 32 + (((quad + gsw) & 3) << 3));
        }
#pragma unroll
        for (int mt = 0; mt < 4; ++mt)
#pragma unroll
            for (int nt = 0; nt < 4; ++nt)
                acc[mt][nt] = __builtin_amdgcn_mfma_f32_16x16x32_bf16(
                    af[mt], bfg[nt], acc[mt][nt], 0, 0, 0);
        __syncthreads();
    }

    const int sel = n0 / 1152;
    const float* bp = (sel == 0) ? b0 : (sel == 1) ? b1 : b2;
    BF16* Cb = C + (size_t)sel * cstride;
    const int nl0 = n0 - sel * 1152;

    float bv[4];
#pragma unroll
    for (int nt = 0; nt < 4; ++nt)
        bv[nt] = bp[nl0 + wn + nt * 16 + l16];
#pragma unroll
    for (int mt = 0; mt < 4; ++mt)
#pragma unroll
        for (int nt = 0; nt < 4; ++nt)
#pragma unroll
            for (int r2 = 0; r2 < 4; ++r2) {
                int row_l = wm + mt * 16 + quad * 4 + r2;
                int col_l = wn + nt * 16 + l16;
                smem[row_l * 128 + col_l] = __float2bfloat16(acc[mt][nt][r2] + bv[nt]);
            }
    __syncthreads();
#pragma unroll
    for (int p = 0; p < 8; ++p) {
        int idx = p * 256 + tid;
        int row = m0 + (idx >> 4);
        if (row < M)
            *(short8*)(Cb + (size_t)row * 1152 + nl0 + (idx & 15) * 8) =
                *(const short8*)(smem + idx * 8);
    }
}

// ---------------------------------------------------------------------------
// Flash attention v2 (unchanged from round 5)
// ---------------------------------------------------------------------------
__global__ __launch_bounds__(256) void attn_flash2(
    const BF16* __restrict__ Q, const BF16* __restrict__ K,
    const BF16* __restrict__ VT, BF16* __restrict__ O)
{
    constexpr int NQ = 729, HDk = 96, DM = 1152, LDV = 736;
    constexpr float NEG = -30000.f;
    __shared__ __align__(16) BF16 Ks[32 * 96];
    __shared__ __align__(16) BF16 Vs[96 * 32];
    __shared__ __align__(16) BF16 Ps[4][32 * 32];

    const int id = blockIdx.x;
    const int xcd = id & 7, slot = id >> 3;
    const int hb = slot / 6, qt = slot - hb * 6;
    const int hg = xcd * 12 + hb;
    const int b = hg / 12, hh = hg - b * 12;

    const int tid = threadIdx.x, wave = tid >> 6, lane = tid & 63;
    const int quad = lane >> 4, l16 = lane & 15;
    const size_t kbase = (size_t)b * (NQ * DM) + (size_t)hh * (NQ * HDk);
    const size_t vbase = (size_t)hg * 96 * LDV;

    const int ckr0 = tid / 12,         ckc0 = (tid - ckr0 * 12) * 8;
    const int c1   = tid + 256;
    const int ckr1 = c1 / 12,          ckc1 = (c1 - ckr1 * 12) * 8;
    const int vr0  = tid >> 2,         vc0  = (tid & 3) * 8;
    const int vr1  = c1 >> 2;
    const BF16* gk0 = K + kbase + (size_t)ckr0 * HDk + ckc0;
    const BF16* gk1 = K + kbase + (size_t)ckr1 * HDk + ckc1;
    const BF16* gv0 = VT + vbase + (size_t)vr0 * LDV + vc0;
    const BF16* gv1 = VT + vbase + (size_t)vr1 * LDV + vc0;
    BF16* lk0 = Ks + (tid & ~63) * 8;
    BF16* lk1 = Ks + (c1 & ~63) * 8;
    BF16* lv0 = Vs + (tid & ~63) * 8;
    BF16* lv1 = Vs + (c1 & ~63) * 8;

    const short8 zero8 = {0, 0, 0, 0, 0, 0, 0, 0};
    const v4f zf = {0.f, 0.f, 0.f, 0.f};
    const float scale = 0.10206207261596577f;  // 96^-0.5

    const int q0w = qt * 128 + wave * 32;
    short8 aq[2][3];
#pragma unroll
    for (int mt = 0; mt < 2; ++mt) {
        int qrow = q0w + mt * 16 + l16;
#pragma unroll
        for (int ks = 0; ks < 3; ++ks)
            aq[mt][ks] = (qrow < NQ)
                ? *(const short8*)(Q + kbase + (size_t)qrow * HDk + ks * 32 + quad * 8)
                : zero8;
    }

    v4f oacc[2][6];
#pragma unroll
    for (int mt = 0; mt < 2; ++mt)
#pragma unroll
        for (int nt = 0; nt < 6; ++nt) oacc[mt][nt] = zf;
    float mrow[2][4], lrow[2][4];
#pragma unroll
    for (int mt = 0; mt < 2; ++mt)
#pragma unroll
        for (int r = 0; r < 4; ++r) { mrow[mt][r] = NEG; lrow[mt][r] = 0.f; }

    for (int kt = 0; kt < 23; ++kt) {
        async_cp16(gk0, lk0);
        async_cp16(gv0, lv0);
        if (tid < 128) {
            async_cp16(gk1, lk1);
            async_cp16(gv1, lv1);
        }
        gk0 += 32 * HDk; gk1 += 32 * HDk; gv0 += 32; gv1 += 32;
        __syncthreads();

        v4f s[2][2];
        s[0][0] = zf; s[0][1] = zf; s[1][0] = zf; s[1][1] = zf;
#pragma unroll
        for (int ks = 0; ks < 3; ++ks) {
            short8 bk0 = *(const short8*)(Ks + l16 * 96 + ks * 32 + quad * 8);
            short8 bk1 = *(const short8*)(Ks + (16 + l16) * 96 + ks * 32 + quad * 8);
#pragma unroll
            for (int mt = 0; mt < 2; ++mt) {
                s[mt][0] = __builtin_amdgcn_mfma_f32_16x16x32_bf16(aq[mt][ks], bk0, s[mt][0], 0, 0, 0);
                s[mt][1] = __builtin_amdgcn_mfma_f32_16x16x32_bf16(aq[mt][ks], bk1, s[mt][1], 0, 0, 0);
            }
        }
        const int k0 = kt * 32;
        const int key0 = k0 + l16, key1 = k0 + 16 + l16;
        BF16* Pw = &Ps[wave][0];
#pragma unroll
        for (int mt = 0; mt < 2; ++mt) {
            float sv0[4], sv1[4], rmx[4], alpha[4], rsum[4], p0[4], p1[4];
#pragma unroll
            for (int r = 0; r < 4; ++r) {
                sv0[r] = (key0 < NQ) ? s[mt][0][r] * scale : NEG;
                sv1[r] = (key1 < NQ) ? s[mt][1][r] * scale : NEG;
                rmx[r] = fmaxf(sv0[r], sv1[r]);
            }
#pragma unroll
            for (int mm = 1; mm < 16; mm <<= 1)
#pragma unroll
                for (int r = 0; r < 4; ++r)
                    rmx[r] = fmaxf(rmx[r], __shfl_xor(rmx[r], mm, 16));
#pragma unroll
            for (int r = 0; r < 4; ++r) {
                float mnew = fmaxf(mrow[mt][r], rmx[r]);
                alpha[r] = __expf(mrow[mt][r] - mnew);
                mrow[mt][r] = mnew;
                p0[r] = __expf(sv0[r] - mnew);
                p1[r] = __expf(sv1[r] - mnew);
                rsum[r] = p0[r] + p1[r];
            }
#pragma unroll
            for (int mm = 1; mm < 16; mm <<= 1)
#pragma unroll
                for (int r = 0; r < 4; ++r)
                    rsum[r] += __shfl_xor(rsum[r], mm, 16);
#pragma unroll
            for (int r = 0; r < 4; ++r) {
                lrow[mt][r] = lrow[mt][r] * alpha[r] + rsum[r];
                Pw[(mt * 16 + quad * 4 + r) * 32 + l16]      = __float2bfloat16(p0[r]);
                Pw[(mt * 16 + quad * 4 + r) * 32 + 16 + l16] = __float2bfloat16(p1[r]);
            }
#pragma unroll
            for (int nt = 0; nt < 6; ++nt)
#pragma unroll
                for (int r = 0; r < 4; ++r) oacc[mt][nt][r] *= alpha[r];
        }
        __syncthreads();

        short8 ap0 = *(const short8*)(Pw + l16 * 32 + quad * 8);
        short8 ap1 = *(const short8*)(Pw + (16 + l16) * 32 + quad * 8);
#pragma unroll
        for (int nt = 0; nt < 6; ++nt) {
            short8 bv = *(const short8*)(Vs + (nt * 16 + l16) * 32 + quad * 8);
            oacc[0][nt] = __builtin_amdgcn_mfma_f32_16x16x32_bf16(ap0, bv, oacc[0][nt], 0, 0, 0);
            oacc[1][nt] = __builtin_amdgcn_mfma_f32_16x16x32_bf16(ap1, bv, oacc[1][nt], 0, 0, 0);
        }
        __syncthreads();
    }

#pragma unroll
    for (int mt = 0; mt < 2; ++mt) {
        const int qb = q0w + mt * 16 + quad * 4;
#pragma unroll
        for (int r = 0; r < 4; ++r) {
            int q = qb + r;
            if (q >= NQ) continue;
            float inv = (lrow[mt][r] > 0.f) ? 1.f / lrow[mt][r] : 0.f;
#pragma unroll
            for (int nt = 0; nt < 6; ++nt)
                O[(size_t)b * (NQ * DM) + (size_t)q * DM + hh * HDk + nt * 16 + l16] =
                    __float2bfloat16(oacc[mt][nt][r] * inv);
        }
    }
}

// ---------------------------------------------------------------------------
// LayerNorm fused kernels (unchanged)
// ---------------------------------------------------------------------------
__device__ __forceinline__ float block_sum256(float v, float* red, int tid)
{
#pragma unroll
    for (int mm = 1; mm < 64; mm <<= 1) v += __shfl_xor(v, mm, 64);
    if ((tid & 63) == 0) red[tid >> 6] = v;
    __syncthreads();
    float r = red[0] + red[1] + red[2] + red[3];
    __syncthreads();
    return r;
}

__global__ __launch_bounds__(256) void ln1_gelu_kernel(
    const BF16* __restrict__ ao, const float* __restrict__ x,
    const float* __restrict__ gw, const float* __restrict__ bw,
    BF16* __restrict__ hout, BF16* __restrict__ gout)
{
    __shared__ float red[4];
    const int row = blockIdx.x, tid = threadIdx.x;
    const BF16* ar = ao + (size_t)row * 1152;
    float vals[5];
    float s = 0.f;
#pragma unroll
    for (int j = 0; j < 5; ++j) {
        int idx = tid + j * 256;
        vals[j] = (idx < 1152) ? __bfloat162float(ar[idx]) : 0.f;
        s += vals[j];
    }
    s = block_sum256(s, red, tid);
    float mu = s * (1.f / 1152.f);
    float vsum = 0.f;
#pragma unroll
    for (int j = 0; j < 5; ++j) {
        int idx = tid + j * 256;
        if (idx < 1152) { float d = vals[j] - mu; vsum += d * d; }
    }
    vsum = block_sum256(vsum, red, tid);
    float rstd = rsqrtf(vsum * (1.f / 1152.f) + 1e-6f);
#pragma unroll
    for (int j = 0; j < 5; ++j) {
        int idx = tid + j * 256;
        if (idx < 1152) {
            float hv = (vals[j] - mu) * rstd * gw[idx] + bw[idx]
                     + x[(size_t)row * 1152 + idx];
            hout[(size_t)row * 1152 + idx] = __float2bfloat16(hv);
            float t = hv;
            float gl = 0.5f * t * (1.f + tanhf(0.7978845608028654f * (t + 0.044715f * t * t * t)));
            gout[(size_t)row * 1152 + idx] = __float2bfloat16(gl);
        }
    }
}

__global__ __launch_bounds__(256) void ln2_kernel(
    const BF16* __restrict__ m2, const BF16* __restrict__ hf,
    const float* __restrict__ gw, const float* __restrict__ bw,
    float* __restrict__ out)
{
    __shared__ float red[4];
    const int row = blockIdx.x, tid = threadIdx.x;
    const BF16* mr = m2 + (size_t)row * 1152;
    float vals[5];
    float s = 0.f;
#pragma unroll
    for (int j = 0; j < 5; ++j) {
        int idx = tid + j * 256;
        vals[j] = (idx < 1152) ? __bfloat162float(mr[idx]) : 0.f;
        s += vals[j];
    }
    s = block_sum256(s, red, tid);
    float mu = s * (1.f / 1152.f);
    float vsum = 0.f;
#pragma unroll
    for (int j = 0; j < 5; ++j) {
        int idx = tid + j * 256;
        if (idx < 1152) { float d = vals[j] - mu; vsum += d * d; }
    }
    vsum = block_sum256(vsum, red, tid);
    float rstd = rsqrtf(vsum * (1.f / 1152.f) + 1e-6f);
#pragma unroll
    for (int j = 0; j < 5; ++j) {
        int idx = tid + j * 256;
        if (idx < 1152) {
            out[(size_t)row * 1152 + idx] =
                (vals[j] - mu) * rstd * gw[idx] + bw[idx]
              + __bfloat162float(hf[(size_t)row * 1152 + idx]);
        }
    }
}

// ---------------------------------------------------------------------------
// Workspace layout (identical to round 5, ~125 MB)
// ---------------------------------------------------------------------------
extern "C" void kernel_launch(void* const* d_in, const int* in_sizes, int n_in,
                              void* d_out, int out_size, void* d_ws, size_t ws_size,
                              hipStream_t stream)
{
    const float* x    = (const float*)d_in[0];
    const float* wq   = (const float*)d_in[1];
    const float* bq   = (const float*)d_in[2];
    const float* wk   = (const float*)d_in[3];
    const float* bk   = (const float*)d_in[4];
    const float* wv   = (const float*)d_in[5];
    const float* bv   = (const float*)d_in[6];
    const float* wo   = (const float*)d_in[7];
    const float* bo   = (const float*)d_in[8];
    const float* ln1g = (const float*)d_in[9];
    const float* ln1b = (const float*)d_in[10];
    const float* wfc1 = (const float*)d_in[11];
    const float* bfc1 = (const float*)d_in[12];
    const float* wfc2 = (const float*)d_in[13];
    const float* bfc2 = (const float*)d_in[14];
    const float* ln2g = (const float*)d_in[15];
    const float* ln2b = (const float*)d_in[16];

    const int T = 8 * 729;           // 5832
    const int D = 1152, HIDP = 4352;
    const size_t TD = (size_t)T * D;
    const size_t WDD = (size_t)D * D;

    BF16* wbq  = (BF16*)d_ws;                  // stacked QKV weights
    BF16* wbk  = wbq + WDD;
    BF16* wbv  = wbk + WDD;
    BF16* wbo  = wbv + WDD;
    BF16* wbf1 = wbo + WDD;
    BF16* wbf2 = wbf1 + (size_t)HIDP * D;
    BF16* xb   = wbf2 + (size_t)D * HIDP;
    BF16* S0   = xb + TD;
    BF16* S1   = S0 + TD;
    BF16* S2   = S1 + TD;
    BF16* S3   = S2 + TD;
    BF16* C0   = S3 + TD;
    BF16* C1   = C0 + TD;
    BF16* M1   = S0;                           // [T*4352] overlays S0..S3
    BF16* VT   = C0;                           // [96*96*736] overlays C0..

    dim3 blk(256);

    // one-shot converts
    const int n4_dd = (int)(WDD / 4);
    cvt4_kernel<<<(n4_dd + 255) / 256, blk, 0, stream>>>(wq, wbq, n4_dd, n4_dd);
    cvt4_kernel<<<(n4_dd + 255) / 256, blk, 0, stream>>>(wk, wbk, n4_dd, n4_dd);
    cvt4_kernel<<<(n4_dd + 255) / 256, blk, 0, stream>>>(wv, wbv, n4_dd, n4_dd);
    cvt4_kernel<<<(n4_dd + 255) / 256, blk, 0, stream>>>(wo, wbo, n4_dd, n4_dd);
    const int n4_f1s = 4304 * 1152 / 4, n4_f1d = HIDP * 1152 / 4;
    cvt4_kernel<<<(n4_f1d + 255) / 256, blk, 0, stream>>>(wfc1, wbf1, n4_f1s, n4_f1d);
    cvt_padcols_kernel<<<(1152 * 1088 + 255) / 256, blk, 0, stream>>>(wfc2, wbf2);
    const int n4_x = (int)(TD / 4);
    cvt4_kernel<<<(n4_x + 255) / 256, blk, 0, stream>>>(x, xb, n4_x, n4_x);

    // fused QKV projection: m fast (48 pad), n slow (27)
    gemm_qkv<<<dim3(48, 27), blk, 0, stream>>>(xb, wbq, bq, bk, bv, S0, TD, T);

    // V transpose + attention
    transpose_v<<<dim3(96, 4), blk, 0, stream>>>(S2, VT);
    attn_flash2<<<576, blk, 0, stream>>>(S0, S1, VT, S3);

    // output projection
    gemm_bt_t<128><<<dim3(48, 9), blk, 0, stream>>>(S3, D, wbo, D, bo, D, C0, D, T, D);

    // LN1 + residual + gelu (gelu in-place over C0)
    ln1_gelu_kernel<<<T, blk, 0, stream>>>(C0, x, ln1g, ln1b, C1, C0);

    // MLP
    gemm_bt_t<128><<<dim3(48, 34), blk, 0, stream>>>(C0, D, wbf1, D, bfc1, 4304, M1, HIDP, T, D);
    gemm_bt_t<64><<<dim3(96, 9), blk, 0, stream>>>(M1, HIDP, wbf2, HIDP, bfc2, D, C0, D, T, HIDP);

    // LN2 + residual -> d_out (fp32)
    ln2_kernel<<<T, blk, 0, stream>>>(C0, C1, ln2g, ln2b, (float*)d_out);
}

// Round 7
// 577.708 us; speedup vs baseline: 3.5357x; 1.0817x over previous
//
#include <hip/hip_runtime.h>
#include <hip/hip_bf16.h>

#define BF16 __hip_bfloat16

typedef short short8 __attribute__((ext_vector_type(8)));
typedef short short4v __attribute__((ext_vector_type(4)));
typedef float v4f __attribute__((ext_vector_type(4)));
typedef float f4 __attribute__((ext_vector_type(4)));

__device__ __forceinline__ short f2bs(float f) {
    __hip_bfloat16 h = __float2bfloat16(f);
    return *(short*)&h;
}

// async global->LDS 16B copy (LDS dest: wave-uniform base + lane*16B)
__device__ __forceinline__ void async_cp16(const BF16* g, BF16* l) {
    __builtin_amdgcn_global_load_lds(
        (const __attribute__((address_space(1))) void*)g,
        (__attribute__((address_space(3))) void*)l,
        16, 0, 0);
}

// ---------------------------------------------------------------------------
// fp32 -> bf16 converters (one-shot per launch)
// ---------------------------------------------------------------------------
__global__ __launch_bounds__(256) void cvt4_kernel(
    const float* __restrict__ src, BF16* __restrict__ dst, int n4src, int n4dst)
{
    int i = blockIdx.x * 256 + threadIdx.x;
    if (i >= n4dst) return;
    short4v o = {0, 0, 0, 0};
    if (i < n4src) {
        f4 v = ((const f4*)src)[i];
        o[0] = f2bs(v.x); o[1] = f2bs(v.y); o[2] = f2bs(v.z); o[3] = f2bs(v.w);
    }
    ((short4v*)dst)[i] = o;
}

// wfc2 [1152][4304] fp32 -> [1152][4352] bf16, pad cols zero
__global__ __launch_bounds__(256) void cvt_padcols_kernel(
    const float* __restrict__ src, BF16* __restrict__ dst)
{
    int i = blockIdx.x * 256 + threadIdx.x;     // i < 1152*1088
    if (i >= 1152 * 1088) return;
    int row = i / 1088;
    int c = (i - row * 1088) * 4;
    short4v o = {0, 0, 0, 0};
    if (c < 4304) {
        f4 v = *(const f4*)(src + (size_t)row * 4304 + c);
        o[0] = f2bs(v.x); o[1] = f2bs(v.y); o[2] = f2bs(v.z); o[3] = f2bs(v.w);
    }
    *(short4v*)(dst + (size_t)row * 4352 + c) = o;
}

// ---------------------------------------------------------------------------
// V transpose v3: per head hg, VT[hg] is [112][768]:
//   rows 0..95  = V head-view transposed (cols >=729 zero)
//   row  96     = ones for valid keys (softmax-l accumulator row)
//   rows 97..111= zeros
// ---------------------------------------------------------------------------
__global__ __launch_bounds__(256) void transpose_v3(
    const BF16* __restrict__ V, BF16* __restrict__ VT)
{
    const int hg = blockIdx.x;           // 0..95
    const int s  = blockIdx.y;           // 0..3 (28 rows each)
    const int b = hg / 12, hh = hg - b * 12;
    const BF16* src = V + (size_t)b * (729 * 1152) + (size_t)hh * (729 * 96);
    BF16* dst = VT + (size_t)hg * 112 * 768;
    const BF16 z = __float2bfloat16(0.f);
    const BF16 one = __float2bfloat16(1.f);
    for (int hd = s * 28; hd < s * 28 + 28; ++hd) {
        for (int kk = threadIdx.x; kk < 768; kk += 256) {
            BF16 val;
            if (hd < 96)       val = (kk < 729) ? src[(size_t)kk * 96 + hd] : z;
            else if (hd == 96) val = (kk < 729) ? one : z;
            else               val = z;
            dst[(size_t)hd * 768 + kk] = val;
        }
    }
}

// ---------------------------------------------------------------------------
// GEMM (templated m-tile), unchanged from round 6.
// ---------------------------------------------------------------------------
template<int TM>
__global__ __launch_bounds__(256) void gemm_bt_t(
    const BF16* __restrict__ A, int lda,
    const BF16* __restrict__ W, int ldb,
    const float* __restrict__ bias, int nbias,
    BF16* __restrict__ C, int ldc,
    int M, int Kr)
{
    constexpr int MT = TM / 32;
    __shared__ __align__(16) BF16 smem[TM * 128];
    BF16* As = smem;
    BF16* Bs = smem + TM * 32;

    const int tid  = threadIdx.x;
    const int lane = tid & 63;
    const int wave = tid >> 6;
    const int quad = lane >> 4;
    const int l16  = lane & 15;
    const int wm   = (wave >> 1) * (TM / 2);
    const int wn   = (wave & 1) * 64;
    const int m0   = blockIdx.x * TM;
    const int n0   = blockIdx.y * 128;
    if (m0 >= M) return;

    const v4f zf = {0.f, 0.f, 0.f, 0.f};
    v4f acc[MT][4];
#pragma unroll
    for (int i = 0; i < MT; ++i)
#pragma unroll
        for (int j = 0; j < 4; ++j) acc[i][j] = zf;

    const int cA0 = tid;
    const int cB0 = tid, cB1 = tid + 256;
    const BF16* gA0 = A + (size_t)(m0 + (cA0 >> 2)) * lda + ((((cA0 & 3) - ((cA0 >> 3) & 3)) & 3) << 3);
    const BF16* gB0 = W + (size_t)(n0 + (cB0 >> 2)) * ldb + ((((cB0 & 3) - ((cB0 >> 3) & 3)) & 3) << 3);
    const BF16* gB1 = W + (size_t)(n0 + (cB1 >> 2)) * ldb + ((((cB1 & 3) - ((cB1 >> 3) & 3)) & 3) << 3);
    BF16* lA0 = As + (cA0 & ~63) * 8;
    BF16* lB0 = Bs + (cB0 & ~63) * 8;
    BF16* lB1 = Bs + (cB1 & ~63) * 8;
    const BF16* gA1 = nullptr; BF16* lA1 = nullptr;
    if constexpr (TM == 128) {
        const int cA1 = tid + 256;
        gA1 = A + (size_t)(m0 + (cA1 >> 2)) * lda + ((((cA1 & 3) - ((cA1 >> 3) & 3)) & 3) << 3);
        lA1 = As + (cA1 & ~63) * 8;
    }

    const int gsw = (l16 >> 1) & 3;
    const int nk = Kr >> 5;
    for (int kt = 0; kt < nk; ++kt) {
        async_cp16(gA0, lA0);
        if constexpr (TM == 128) async_cp16(gA1, lA1);
        async_cp16(gB0, lB0);
        async_cp16(gB1, lB1);
        gA0 += 32; gB0 += 32; gB1 += 32;
        if constexpr (TM == 128) gA1 += 32;
        __syncthreads();

        short8 af[MT], bfg[4];
#pragma unroll
        for (int mt = 0; mt < MT; ++mt) {
            int row = wm + mt * 16 + l16;
            af[mt] = *(const short8*)(As + row * 32 + (((quad + gsw) & 3) << 3));
        }
#pragma unroll
        for (int nt = 0; nt < 4; ++nt) {
            int row = wn + nt * 16 + l16;
            bfg[nt] = *(const short8*)(Bs + row * 32 + (((quad + gsw) & 3) << 3));
        }
#pragma unroll
        for (int mt = 0; mt < MT; ++mt)
#pragma unroll
            for (int nt = 0; nt < 4; ++nt)
                acc[mt][nt] = __builtin_amdgcn_mfma_f32_16x16x32_bf16(
                    af[mt], bfg[nt], acc[mt][nt], 0, 0, 0);
        __syncthreads();
    }

    float bv[4];
#pragma unroll
    for (int nt = 0; nt < 4; ++nt) {
        int col = n0 + wn + nt * 16 + l16;
        bv[nt] = (col < nbias) ? bias[col] : 0.f;
    }
#pragma unroll
    for (int mt = 0; mt < MT; ++mt)
#pragma unroll
        for (int nt = 0; nt < 4; ++nt)
#pragma unroll
            for (int r2 = 0; r2 < 4; ++r2) {
                int row_l = wm + mt * 16 + quad * 4 + r2;
                int col_l = wn + nt * 16 + l16;
                smem[row_l * 128 + col_l] = __float2bfloat16(acc[mt][nt][r2] + bv[nt]);
            }
    __syncthreads();
#pragma unroll
    for (int p = 0; p < TM / 16; ++p) {
        int idx = p * 256 + tid;
        int row = m0 + (idx >> 4);
        if (row < M)
            *(short8*)(C + (size_t)row * ldc + n0 + (idx & 15) * 8) =
                *(const short8*)(smem + idx * 8);
    }
}

// ---------------------------------------------------------------------------
// Fused QKV GEMM (unchanged from round 6)
// ---------------------------------------------------------------------------
__global__ __launch_bounds__(256) void gemm_qkv(
    const BF16* __restrict__ A,
    const BF16* __restrict__ W,
    const float* __restrict__ b0, const float* __restrict__ b1,
    const float* __restrict__ b2,
    BF16* __restrict__ C, size_t cstride, int M)
{
    __shared__ __align__(16) BF16 smem[128 * 128];
    BF16* As = smem;
    BF16* Bs = smem + 128 * 32;

    const int tid  = threadIdx.x;
    const int lane = tid & 63;
    const int wave = tid >> 6;
    const int quad = lane >> 4;
    const int l16  = lane & 15;
    const int wm   = (wave >> 1) * 64;
    const int wn   = (wave & 1) * 64;
    const int m0   = blockIdx.x * 128;
    const int n0   = blockIdx.y * 128;
    if (m0 >= M) return;

    const v4f zf = {0.f, 0.f, 0.f, 0.f};
    v4f acc[4][4];
#pragma unroll
    for (int i = 0; i < 4; ++i)
#pragma unroll
        for (int j = 0; j < 4; ++j) acc[i][j] = zf;

    const int cA0 = tid, cA1 = tid + 256;
    const BF16* gA0 = A + (size_t)(m0 + (cA0 >> 2)) * 1152 + ((((cA0 & 3) - ((cA0 >> 3) & 3)) & 3) << 3);
    const BF16* gA1 = A + (size_t)(m0 + (cA1 >> 2)) * 1152 + ((((cA1 & 3) - ((cA1 >> 3) & 3)) & 3) << 3);
    const BF16* gB0 = W + (size_t)(n0 + (cA0 >> 2)) * 1152 + ((((cA0 & 3) - ((cA0 >> 3) & 3)) & 3) << 3);
    const BF16* gB1 = W + (size_t)(n0 + (cA1 >> 2)) * 1152 + ((((cA1 & 3) - ((cA1 >> 3) & 3)) & 3) << 3);
    BF16* lA0 = As + (cA0 & ~63) * 8;
    BF16* lA1 = As + (cA1 & ~63) * 8;
    BF16* lB0 = Bs + (cA0 & ~63) * 8;
    BF16* lB1 = Bs + (cA1 & ~63) * 8;

    const int gsw = (l16 >> 1) & 3;
    for (int kt = 0; kt < 36; ++kt) {
        async_cp16(gA0, lA0);
        async_cp16(gA1, lA1);
        async_cp16(gB0, lB0);
        async_cp16(gB1, lB1);
        gA0 += 32; gA1 += 32; gB0 += 32; gB1 += 32;
        __syncthreads();

        short8 af[4], bfg[4];
#pragma unroll
        for (int mt = 0; mt < 4; ++mt) {
            int row = wm + mt * 16 + l16;
            af[mt] = *(const short8*)(As + row * 32 + (((quad + gsw) & 3) << 3));
        }
#pragma unroll
        for (int nt = 0; nt < 4; ++nt) {
            int row = wn + nt * 16 + l16;
            bfg[nt] = *(const short8*)(Bs + row * 32 + (((quad + gsw) & 3) << 3));
        }
#pragma unroll
        for (int mt = 0; mt < 4; ++mt)
#pragma unroll
            for (int nt = 0; nt < 4; ++nt)
                acc[mt][nt] = __builtin_amdgcn_mfma_f32_16x16x32_bf16(
                    af[mt], bfg[nt], acc[mt][nt], 0, 0, 0);
        __syncthreads();
    }

    const int sel = n0 / 1152;
    const float* bp = (sel == 0) ? b0 : (sel == 1) ? b1 : b2;
    BF16* Cb = C + (size_t)sel * cstride;
    const int nl0 = n0 - sel * 1152;

    float bv[4];
#pragma unroll
    for (int nt = 0; nt < 4; ++nt)
        bv[nt] = bp[nl0 + wn + nt * 16 + l16];
#pragma unroll
    for (int mt = 0; mt < 4; ++mt)
#pragma unroll
        for (int nt = 0; nt < 4; ++nt)
#pragma unroll
            for (int r2 = 0; r2 < 4; ++r2) {
                int row_l = wm + mt * 16 + quad * 4 + r2;
                int col_l = wn + nt * 16 + l16;
                smem[row_l * 128 + col_l] = __float2bfloat16(acc[mt][nt][r2] + bv[nt]);
            }
    __syncthreads();
#pragma unroll
    for (int p = 0; p < 8; ++p) {
        int idx = p * 256 + tid;
        int row = m0 + (idx >> 4);
        if (row < M)
            *(short8*)(Cb + (size_t)row * 1152 + nl0 + (idx & 15) * 8) =
                *(const short8*)(smem + idx * 8);
    }
}

// ---------------------------------------------------------------------------
// Flash attention v3: 64-key tiles (12 iters), no-max softmax (exp2, scores
// bounded), l accumulated via ones-row in VT through the PV MFMA, conflict-
// free LDS (Ks stride 104 manual, Vs 8-group XOR async, Ps stride 72),
// per-wave P ordering via s_waitcnt (no barrier). 2 barriers/iter.
// ---------------------------------------------------------------------------
__global__ __launch_bounds__(256) void attn_flash3(
    const BF16* __restrict__ Q, const BF16* __restrict__ K,
    const BF16* __restrict__ VT, BF16* __restrict__ O)
{
    constexpr int NQ = 729, HDk = 96, DM = 1152, LDV = 768;
    __shared__ __align__(16) BF16 Ks[64 * 104];    // [64 keys][96 hd] pad 104
    __shared__ __align__(16) BF16 Vs[112 * 64];    // [112 hd][64 keys] XOR-swz
    __shared__ __align__(16) BF16 Ps[4][32 * 72];  // per-wave P [32 q][64 k] pad 72

    const int id = blockIdx.x;                 // 576
    const int xcd = id & 7, slot = id >> 3;
    const int hb = slot / 6, qt = slot - hb * 6;
    const int hg = xcd * 12 + hb;
    const int b = hg / 12, hh = hg - b * 12;

    const int tid = threadIdx.x, wave = tid >> 6, lane = tid & 63;
    const int quad = lane >> 4, l16 = lane & 15;
    const size_t kbase = (size_t)b * (NQ * DM) + (size_t)hh * (NQ * HDk);
    const size_t vbase = (size_t)hg * 112 * LDV;

    const short8 zero8 = {0, 0, 0, 0, 0, 0, 0, 0};
    const v4f zf = {0.f, 0.f, 0.f, 0.f};
    const float C2 = 0.14724445f;   // (1/sqrt(96)) * log2(e)

    // Q fragments (2 m-tiles x 3 k-slices), loaded once
    const int q0w = qt * 128 + wave * 32;
    short8 aq[2][3];
#pragma unroll
    for (int mt = 0; mt < 2; ++mt) {
        int qrow = q0w + mt * 16 + l16;
#pragma unroll
        for (int ks = 0; ks < 3; ++ks)
            aq[mt][ks] = (qrow < NQ)
                ? *(const short8*)(Q + kbase + (size_t)qrow * HDk + ks * 32 + quad * 8)
                : zero8;
    }

    // K manual staging coords: chunk c -> key=c/12, group g=c%12
    int kk_[3], kg_[3];
#pragma unroll
    for (int i = 0; i < 3; ++i) {
        int c = tid + i * 256;
        kk_[i] = c / 12; kg_[i] = c - kk_[i] * 12;
    }
    // Vs async coords: instr q covers hd rows q*8..q*8+7; lane: hd=q*8+(lane>>3),
    // LDS slot=lane&7 holds source key-group (slot - hd)&7
    int vq_[4], vgr_[4], vhd_[4];
#pragma unroll
    for (int i = 0; i < 4; ++i) {
        int q = wave + 4 * i;
        vq_[i] = q;
        int hd = q * 8 + (lane >> 3);
        vhd_[i] = hd;
        vgr_[i] = ((lane & 7) - hd) & 7;
    }

    v4f oacc[2][7];
#pragma unroll
    for (int mt = 0; mt < 2; ++mt)
#pragma unroll
        for (int nt = 0; nt < 7; ++nt) oacc[mt][nt] = zf;

    for (int kt = 0; kt < 12; ++kt) {
        const int k0 = kt * 64;
        // ---- stage Vs (async, XOR-swizzled source groups) ----
#pragma unroll
        for (int i = 0; i < 4; ++i) {
            if (vq_[i] < 14)
                async_cp16(VT + vbase + (size_t)vhd_[i] * LDV + k0 + vgr_[i] * 8,
                           Vs + vq_[i] * 512);
        }
        // ---- stage Ks (manual, padded stride 104) ----
#pragma unroll
        for (int i = 0; i < 3; ++i) {
            short8 v = *(const short8*)(K + kbase + (size_t)(k0 + kk_[i]) * HDk + kg_[i] * 8);
            *(short8*)(Ks + kk_[i] * 104 + kg_[i] * 8) = v;
        }
        __syncthreads();

        // ---- S = Q K^T : 32q x 64k per wave ----
        v4f s[2][4];
#pragma unroll
        for (int mt = 0; mt < 2; ++mt)
#pragma unroll
            for (int nt = 0; nt < 4; ++nt) s[mt][nt] = zf;
#pragma unroll
        for (int ks = 0; ks < 3; ++ks)
#pragma unroll
            for (int nt = 0; nt < 4; ++nt) {
                short8 bk = *(const short8*)(Ks + (nt * 16 + l16) * 104 + ks * 32 + quad * 8);
#pragma unroll
                for (int mt = 0; mt < 2; ++mt)
                    s[mt][nt] = __builtin_amdgcn_mfma_f32_16x16x32_bf16(
                        aq[mt][ks], bk, s[mt][nt], 0, 0, 0);
            }

        // ---- P = exp2(s*C2) -> Ps (C-layout write) ----
        BF16* Pw = &Ps[wave][0];
#pragma unroll
        for (int mt = 0; mt < 2; ++mt)
#pragma unroll
            for (int nt = 0; nt < 4; ++nt)
#pragma unroll
                for (int r = 0; r < 4; ++r)
                    Pw[(mt * 16 + quad * 4 + r) * 72 + nt * 16 + l16] =
                        __float2bfloat16(exp2f(s[mt][nt][r] * C2));
        asm volatile("s_waitcnt lgkmcnt(0)" ::: "memory");  // wave-local P order

        // ---- O += P V : A=P (re-read in A-layout), B=Vs ----
        short8 ap[2][2];
#pragma unroll
        for (int mt = 0; mt < 2; ++mt)
#pragma unroll
            for (int kc = 0; kc < 2; ++kc)
                ap[mt][kc] = *(const short8*)(Pw + (mt * 16 + l16) * 72 + kc * 32 + quad * 8);
#pragma unroll
        for (int nt = 0; nt < 7; ++nt) {
            int hd = nt * 16 + l16;
#pragma unroll
            for (int kc = 0; kc < 2; ++kc) {
                short8 bv = *(const short8*)(Vs + hd * 64 + (((kc * 4 + quad) + hd & 7) & 7) * 8);
#pragma unroll
                for (int mt = 0; mt < 2; ++mt)
                    oacc[mt][nt] = __builtin_amdgcn_mfma_f32_16x16x32_bf16(
                        ap[mt][kc], bv, oacc[mt][nt], 0, 0, 0);
            }
        }
        __syncthreads();   // protect Ks/Vs before next staging
    }

    // ---- epilogue: l = oacc[:,6] col0 (ones-row), broadcast within quad ----
#pragma unroll
    for (int mt = 0; mt < 2; ++mt) {
        const int qb = q0w + mt * 16 + quad * 4;
#pragma unroll
        for (int r = 0; r < 4; ++r) {
            int q = qb + r;
            float lv = __shfl(oacc[mt][6][r], quad << 4, 64);
            float inv = (lv > 0.f) ? 1.f / lv : 0.f;
            if (q >= NQ) continue;
#pragma unroll
            for (int nt = 0; nt < 6; ++nt)
                O[(size_t)b * (NQ * DM) + (size_t)q * DM + hh * HDk + nt * 16 + l16] =
                    __float2bfloat16(oacc[mt][nt][r] * inv);
        }
    }
}

// ---------------------------------------------------------------------------
// LayerNorm fused kernels (unchanged)
// ---------------------------------------------------------------------------
__device__ __forceinline__ float block_sum256(float v, float* red, int tid)
{
#pragma unroll
    for (int mm = 1; mm < 64; mm <<= 1) v += __shfl_xor(v, mm, 64);
    if ((tid & 63) == 0) red[tid >> 6] = v;
    __syncthreads();
    float r = red[0] + red[1] + red[2] + red[3];
    __syncthreads();
    return r;
}

__global__ __launch_bounds__(256) void ln1_gelu_kernel(
    const BF16* __restrict__ ao, const float* __restrict__ x,
    const float* __restrict__ gw, const float* __restrict__ bw,
    BF16* __restrict__ hout, BF16* __restrict__ gout)
{
    __shared__ float red[4];
    const int row = blockIdx.x, tid = threadIdx.x;
    const BF16* ar = ao + (size_t)row * 1152;
    float vals[5];
    float s = 0.f;
#pragma unroll
    for (int j = 0; j < 5; ++j) {
        int idx = tid + j * 256;
        vals[j] = (idx < 1152) ? __bfloat162float(ar[idx]) : 0.f;
        s += vals[j];
    }
    s = block_sum256(s, red, tid);
    float mu = s * (1.f / 1152.f);
    float vsum = 0.f;
#pragma unroll
    for (int j = 0; j < 5; ++j) {
        int idx = tid + j * 256;
        if (idx < 1152) { float d = vals[j] - mu; vsum += d * d; }
    }
    vsum = block_sum256(vsum, red, tid);
    float rstd = rsqrtf(vsum * (1.f / 1152.f) + 1e-6f);
#pragma unroll
    for (int j = 0; j < 5; ++j) {
        int idx = tid + j * 256;
        if (idx < 1152) {
            float hv = (vals[j] - mu) * rstd * gw[idx] + bw[idx]
                     + x[(size_t)row * 1152 + idx];
            hout[(size_t)row * 1152 + idx] = __float2bfloat16(hv);
            float t = hv;
            float gl = 0.5f * t * (1.f + tanhf(0.7978845608028654f * (t + 0.044715f * t * t * t)));
            gout[(size_t)row * 1152 + idx] = __float2bfloat16(gl);
        }
    }
}

__global__ __launch_bounds__(256) void ln2_kernel(
    const BF16* __restrict__ m2, const BF16* __restrict__ hf,
    const float* __restrict__ gw, const float* __restrict__ bw,
    float* __restrict__ out)
{
    __shared__ float red[4];
    const int row = blockIdx.x, tid = threadIdx.x;
    const BF16* mr = m2 + (size_t)row * 1152;
    float vals[5];
    float s = 0.f;
#pragma unroll
    for (int j = 0; j < 5; ++j) {
        int idx = tid + j * 256;
        vals[j] = (idx < 1152) ? __bfloat162float(mr[idx]) : 0.f;
        s += vals[j];
    }
    s = block_sum256(s, red, tid);
    float mu = s * (1.f / 1152.f);
    float vsum = 0.f;
#pragma unroll
    for (int j = 0; j < 5; ++j) {
        int idx = tid + j * 256;
        if (idx < 1152) { float d = vals[j] - mu; vsum += d * d; }
    }
    vsum = block_sum256(vsum, red, tid);
    float rstd = rsqrtf(vsum * (1.f / 1152.f) + 1e-6f);
#pragma unroll
    for (int j = 0; j < 5; ++j) {
        int idx = tid + j * 256;
        if (idx < 1152) {
            out[(size_t)row * 1152 + idx] =
                (vals[j] - mu) * rstd * gw[idx] + bw[idx]
              + __bfloat162float(hf[(size_t)row * 1152 + idx]);
        }
    }
}

// ---------------------------------------------------------------------------
// Workspace layout (~125 MB). VT [96][112][768] overlays C0+part of C1
// (dead until wo-GEMM / ln1 run, which happen after attention).
// ---------------------------------------------------------------------------
extern "C" void kernel_launch(void* const* d_in, const int* in_sizes, int n_in,
                              void* d_out, int out_size, void* d_ws, size_t ws_size,
                              hipStream_t stream)
{
    const float* x    = (const float*)d_in[0];
    const float* wq   = (const float*)d_in[1];
    const float* bq   = (const float*)d_in[2];
    const float* wk   = (const float*)d_in[3];
    const float* bk   = (const float*)d_in[4];
    const float* wv   = (const float*)d_in[5];
    const float* bv   = (const float*)d_in[6];
    const float* wo   = (const float*)d_in[7];
    const float* bo   = (const float*)d_in[8];
    const float* ln1g = (const float*)d_in[9];
    const float* ln1b = (const float*)d_in[10];
    const float* wfc1 = (const float*)d_in[11];
    const float* bfc1 = (const float*)d_in[12];
    const float* wfc2 = (const float*)d_in[13];
    const float* bfc2 = (const float*)d_in[14];
    const float* ln2g = (const float*)d_in[15];
    const float* ln2b = (const float*)d_in[16];

    const int T = 8 * 729;           // 5832
    const int D = 1152, HIDP = 4352;
    const size_t TD = (size_t)T * D;
    const size_t WDD = (size_t)D * D;

    BF16* wbq  = (BF16*)d_ws;                  // stacked QKV weights
    BF16* wbk  = wbq + WDD;
    BF16* wbv  = wbk + WDD;
    BF16* wbo  = wbv + WDD;
    BF16* wbf1 = wbo + WDD;
    BF16* wbf2 = wbf1 + (size_t)HIDP * D;
    BF16* xb   = wbf2 + (size_t)D * HIDP;
    BF16* S0   = xb + TD;
    BF16* S1   = S0 + TD;
    BF16* S2   = S1 + TD;
    BF16* S3   = S2 + TD;
    BF16* C0   = S3 + TD;
    BF16* C1   = C0 + TD;
    BF16* M1   = S0;                           // [T*4352] overlays S0..S3
    BF16* VT   = C0;                           // [96*112*768] overlays C0+C1 head

    dim3 blk(256);

    // one-shot converts
    const int n4_dd = (int)(WDD / 4);
    cvt4_kernel<<<(n4_dd + 255) / 256, blk, 0, stream>>>(wq, wbq, n4_dd, n4_dd);
    cvt4_kernel<<<(n4_dd + 255) / 256, blk, 0, stream>>>(wk, wbk, n4_dd, n4_dd);
    cvt4_kernel<<<(n4_dd + 255) / 256, blk, 0, stream>>>(wv, wbv, n4_dd, n4_dd);
    cvt4_kernel<<<(n4_dd + 255) / 256, blk, 0, stream>>>(wo, wbo, n4_dd, n4_dd);
    const int n4_f1s = 4304 * 1152 / 4, n4_f1d = HIDP * 1152 / 4;
    cvt4_kernel<<<(n4_f1d + 255) / 256, blk, 0, stream>>>(wfc1, wbf1, n4_f1s, n4_f1d);
    cvt_padcols_kernel<<<(1152 * 1088 + 255) / 256, blk, 0, stream>>>(wfc2, wbf2);
    const int n4_x = (int)(TD / 4);
    cvt4_kernel<<<(n4_x + 255) / 256, blk, 0, stream>>>(x, xb, n4_x, n4_x);

    // fused QKV projection: m fast (48 pad), n slow (27)
    gemm_qkv<<<dim3(48, 27), blk, 0, stream>>>(xb, wbq, bq, bk, bv, S0, TD, T);

    // V transpose (+ones row) + attention
    transpose_v3<<<dim3(96, 4), blk, 0, stream>>>(S2, VT);
    attn_flash3<<<576, blk, 0, stream>>>(S0, S1, VT, S3);

    // output projection
    gemm_bt_t<128><<<dim3(48, 9), blk, 0, stream>>>(S3, D, wbo, D, bo, D, C0, D, T, D);

    // LN1 + residual + gelu (gelu in-place over C0)
    ln1_gelu_kernel<<<T, blk, 0, stream>>>(C0, x, ln1g, ln1b, C1, C0);

    // MLP
    gemm_bt_t<128><<<dim3(48, 34), blk, 0, stream>>>(C0, D, wbf1, D, bfc1, 4304, M1, HIDP, T, D);
    gemm_bt_t<64><<<dim3(96, 9), blk, 0, stream>>>(M1, HIDP, wbf2, HIDP, bfc2, D, C0, D, T, HIDP);

    // LN2 + residual -> d_out (fp32)
    ln2_kernel<<<T, blk, 0, stream>>>(C0, C1, ln2g, ln2b, (float*)d_out);
}

// Round 8
// 540.785 us; speedup vs baseline: 3.7771x; 1.0683x over previous
//
#include <hip/hip_runtime.h>
#include <hip/hip_bf16.h>

#define BF16 __hip_bfloat16

typedef short short8 __attribute__((ext_vector_type(8)));
typedef short short4v __attribute__((ext_vector_type(4)));
typedef float v4f __attribute__((ext_vector_type(4)));
typedef float f4 __attribute__((ext_vector_type(4)));

__device__ __forceinline__ short f2bs(float f) {
    __hip_bfloat16 h = __float2bfloat16(f);
    return *(short*)&h;
}

// async global->LDS 16B copy (LDS dest: wave-uniform base + lane*16B)
__device__ __forceinline__ void async_cp16(const BF16* g, BF16* l) {
    __builtin_amdgcn_global_load_lds(
        (const __attribute__((address_space(1))) void*)g,
        (__attribute__((address_space(3))) void*)l,
        16, 0, 0);
}

// ---------------------------------------------------------------------------
// fp32 -> bf16 converters (one-shot per launch)
// ---------------------------------------------------------------------------
__global__ __launch_bounds__(256) void cvt4_kernel(
    const float* __restrict__ src, BF16* __restrict__ dst, int n4src, int n4dst)
{
    int i = blockIdx.x * 256 + threadIdx.x;
    if (i >= n4dst) return;
    short4v o = {0, 0, 0, 0};
    if (i < n4src) {
        f4 v = ((const f4*)src)[i];
        o[0] = f2bs(v.x); o[1] = f2bs(v.y); o[2] = f2bs(v.z); o[3] = f2bs(v.w);
    }
    ((short4v*)dst)[i] = o;
}

// wfc2 [1152][4304] fp32 -> [1152][4352] bf16, pad cols zero
__global__ __launch_bounds__(256) void cvt_padcols_kernel(
    const float* __restrict__ src, BF16* __restrict__ dst)
{
    int i = blockIdx.x * 256 + threadIdx.x;     // i < 1152*1088
    if (i >= 1152 * 1088) return;
    int row = i / 1088;
    int c = (i - row * 1088) * 4;
    short4v o = {0, 0, 0, 0};
    if (c < 4304) {
        f4 v = *(const f4*)(src + (size_t)row * 4304 + c);
        o[0] = f2bs(v.x); o[1] = f2bs(v.y); o[2] = f2bs(v.z); o[3] = f2bs(v.w);
    }
    *(short4v*)(dst + (size_t)row * 4352 + c) = o;
}

// ---------------------------------------------------------------------------
// V transpose v3: per head hg, VT[hg] is [112][768]:
//   rows 0..95 = V head-view transposed; row 96 = ones (l-row); rest zero.
// ---------------------------------------------------------------------------
__global__ __launch_bounds__(256) void transpose_v3(
    const BF16* __restrict__ V, BF16* __restrict__ VT)
{
    const int hg = blockIdx.x;           // 0..95
    const int s  = blockIdx.y;           // 0..3 (28 rows each)
    const int b = hg / 12, hh = hg - b * 12;
    const BF16* src = V + (size_t)b * (729 * 1152) + (size_t)hh * (729 * 96);
    BF16* dst = VT + (size_t)hg * 112 * 768;
    const BF16 z = __float2bfloat16(0.f);
    const BF16 one = __float2bfloat16(1.f);
    for (int hd = s * 28; hd < s * 28 + 28; ++hd) {
        for (int kk = threadIdx.x; kk < 768; kk += 256) {
            BF16 val;
            if (hd < 96)       val = (kk < 729) ? src[(size_t)kk * 96 + hd] : z;
            else if (hd == 96) val = (kk < 729) ? one : z;
            else               val = z;
            dst[(size_t)hd * 768 + kk] = val;
        }
    }
}

// ---------------------------------------------------------------------------
// GEMM v2: TM x 128 tile, BK=64, global_load_lds staging with mod-8 XOR
// swizzle (logical k-group g of row r stored at slot (g+r)&7 -> conflict-free
// ds_read_b128 at 128B row stride), coalesced LDS-staged epilogue.
// Grid: blockIdx.x = m-tile (fast), blockIdx.y = n-tile (slow, W L2-resident).
// Nr == gridDim.y*128 exactly; Kr % 64 == 0; A rows may be read up to TM-1
// past M (backed by adjacent ws memory).
// ---------------------------------------------------------------------------
template<int TM>
__global__ __launch_bounds__(256) void gemm_bt_t(
    const BF16* __restrict__ A, int lda,
    const BF16* __restrict__ W, int ldb,
    const float* __restrict__ bias, int nbias,
    BF16* __restrict__ C, int ldc,
    int M, int Kr)
{
    constexpr int MT = TM / 32;          // m-frags per wave (and A chunks/thread)
    __shared__ __align__(16) BF16 smem[(TM + 128) * 64];
    BF16* As = smem;                     // [TM][64] swizzled
    BF16* Bs = smem + TM * 64;           // [128][64] swizzled

    const int tid  = threadIdx.x;
    const int lane = tid & 63;
    const int wave = tid >> 6;
    const int quad = lane >> 4;
    const int l16  = lane & 15;
    const int wm   = (wave >> 1) * (TM / 2);
    const int wn   = (wave & 1) * 64;
    const int m0   = blockIdx.x * TM;
    const int n0   = blockIdx.y * 128;
    if (m0 >= M) return;

    const v4f zf = {0.f, 0.f, 0.f, 0.f};
    v4f acc[MT][4];
#pragma unroll
    for (int i = 0; i < MT; ++i)
#pragma unroll
        for (int j = 0; j < 4; ++j) acc[i][j] = zf;

    // staging: chunk c -> row=c>>3, slot=c&7, source group=(slot-row)&7
    const BF16* gA[MT]; BF16* lA[MT];
#pragma unroll
    for (int i = 0; i < MT; ++i) {
        int c = tid + i * 256;
        gA[i] = A + (size_t)(m0 + (c >> 3)) * lda + ((((c & 7) - (c >> 3)) & 7) << 3);
        lA[i] = As + (c & ~63) * 8;
    }
    const BF16* gB[4]; BF16* lB[4];
#pragma unroll
    for (int i = 0; i < 4; ++i) {
        int c = tid + i * 256;
        gB[i] = W + (size_t)(n0 + (c >> 3)) * ldb + ((((c & 7) - (c >> 3)) & 7) << 3);
        lB[i] = Bs + (c & ~63) * 8;
    }

    const int nk = Kr >> 6;
    for (int kt = 0; kt < nk; ++kt) {
#pragma unroll
        for (int i = 0; i < MT; ++i) { async_cp16(gA[i], lA[i]); gA[i] += 64; }
#pragma unroll
        for (int i = 0; i < 4; ++i)  { async_cp16(gB[i], lB[i]); gB[i] += 64; }
        __syncthreads();

#pragma unroll
        for (int ks = 0; ks < 2; ++ks) {
            short8 af[MT], bfg[4];
#pragma unroll
            for (int mt = 0; mt < MT; ++mt) {
                int row = wm + mt * 16 + l16;
                af[mt] = *(const short8*)(As + row * 64 + ((((ks << 2) | quad) + row & 7) & 7) * 8);
            }
#pragma unroll
            for (int nt = 0; nt < 4; ++nt) {
                int row = wn + nt * 16 + l16;
                bfg[nt] = *(const short8*)(Bs + row * 64 + ((((ks << 2) | quad) + row & 7) & 7) * 8);
            }
#pragma unroll
            for (int mt = 0; mt < MT; ++mt)
#pragma unroll
                for (int nt = 0; nt < 4; ++nt)
                    acc[mt][nt] = __builtin_amdgcn_mfma_f32_16x16x32_bf16(
                        af[mt], bfg[nt], acc[mt][nt], 0, 0, 0);
        }
        __syncthreads();
    }

    // coalesced epilogue: tile -> LDS (bf16 + bias) -> short8 row stores
    float bv[4];
#pragma unroll
    for (int nt = 0; nt < 4; ++nt) {
        int col = n0 + wn + nt * 16 + l16;
        bv[nt] = (col < nbias) ? bias[col] : 0.f;
    }
#pragma unroll
    for (int mt = 0; mt < MT; ++mt)
#pragma unroll
        for (int nt = 0; nt < 4; ++nt)
#pragma unroll
            for (int r2 = 0; r2 < 4; ++r2) {
                int row_l = wm + mt * 16 + quad * 4 + r2;
                int col_l = wn + nt * 16 + l16;
                smem[row_l * 128 + col_l] = __float2bfloat16(acc[mt][nt][r2] + bv[nt]);
            }
    __syncthreads();
#pragma unroll
    for (int p = 0; p < TM / 16; ++p) {
        int idx = p * 256 + tid;
        int row = m0 + (idx >> 4);
        if (row < M)
            *(short8*)(C + (size_t)row * ldc + n0 + (idx & 15) * 8) =
                *(const short8*)(smem + idx * 8);
    }
}

// ---------------------------------------------------------------------------
// Fused QKV GEMM: BK=64 + mod-8 swizzle; W stacked [3456][1152]; output
// routed to three [T,1152] buffers by sel = n0/1152.
// ---------------------------------------------------------------------------
__global__ __launch_bounds__(256) void gemm_qkv(
    const BF16* __restrict__ A,
    const BF16* __restrict__ W,
    const float* __restrict__ b0, const float* __restrict__ b1,
    const float* __restrict__ b2,
    BF16* __restrict__ C, size_t cstride, int M)
{
    __shared__ __align__(16) BF16 smem[256 * 64];
    BF16* As = smem;
    BF16* Bs = smem + 128 * 64;

    const int tid  = threadIdx.x;
    const int lane = tid & 63;
    const int wave = tid >> 6;
    const int quad = lane >> 4;
    const int l16  = lane & 15;
    const int wm   = (wave >> 1) * 64;
    const int wn   = (wave & 1) * 64;
    const int m0   = blockIdx.x * 128;
    const int n0   = blockIdx.y * 128;
    if (m0 >= M) return;

    const v4f zf = {0.f, 0.f, 0.f, 0.f};
    v4f acc[4][4];
#pragma unroll
    for (int i = 0; i < 4; ++i)
#pragma unroll
        for (int j = 0; j < 4; ++j) acc[i][j] = zf;

    const BF16* gA[4]; BF16* lA[4];
    const BF16* gB[4]; BF16* lB[4];
#pragma unroll
    for (int i = 0; i < 4; ++i) {
        int c = tid + i * 256;
        int src = ((((c & 7) - (c >> 3)) & 7) << 3);
        gA[i] = A + (size_t)(m0 + (c >> 3)) * 1152 + src;
        gB[i] = W + (size_t)(n0 + (c >> 3)) * 1152 + src;
        lA[i] = As + (c & ~63) * 8;
        lB[i] = Bs + (c & ~63) * 8;
    }

    for (int kt = 0; kt < 18; ++kt) {
#pragma unroll
        for (int i = 0; i < 4; ++i) { async_cp16(gA[i], lA[i]); gA[i] += 64; }
#pragma unroll
        for (int i = 0; i < 4; ++i) { async_cp16(gB[i], lB[i]); gB[i] += 64; }
        __syncthreads();

#pragma unroll
        for (int ks = 0; ks < 2; ++ks) {
            short8 af[4], bfg[4];
#pragma unroll
            for (int mt = 0; mt < 4; ++mt) {
                int row = wm + mt * 16 + l16;
                af[mt] = *(const short8*)(As + row * 64 + ((((ks << 2) | quad) + row & 7) & 7) * 8);
            }
#pragma unroll
            for (int nt = 0; nt < 4; ++nt) {
                int row = wn + nt * 16 + l16;
                bfg[nt] = *(const short8*)(Bs + row * 64 + ((((ks << 2) | quad) + row & 7) & 7) * 8);
            }
#pragma unroll
            for (int mt = 0; mt < 4; ++mt)
#pragma unroll
                for (int nt = 0; nt < 4; ++nt)
                    acc[mt][nt] = __builtin_amdgcn_mfma_f32_16x16x32_bf16(
                        af[mt], bfg[nt], acc[mt][nt], 0, 0, 0);
        }
        __syncthreads();
    }

    const int sel = n0 / 1152;
    const float* bp = (sel == 0) ? b0 : (sel == 1) ? b1 : b2;
    BF16* Cb = C + (size_t)sel * cstride;
    const int nl0 = n0 - sel * 1152;

    float bv[4];
#pragma unroll
    for (int nt = 0; nt < 4; ++nt)
        bv[nt] = bp[nl0 + wn + nt * 16 + l16];
#pragma unroll
    for (int mt = 0; mt < 4; ++mt)
#pragma unroll
        for (int nt = 0; nt < 4; ++nt)
#pragma unroll
            for (int r2 = 0; r2 < 4; ++r2) {
                int row_l = wm + mt * 16 + quad * 4 + r2;
                int col_l = wn + nt * 16 + l16;
                smem[row_l * 128 + col_l] = __float2bfloat16(acc[mt][nt][r2] + bv[nt]);
            }
    __syncthreads();
#pragma unroll
    for (int p = 0; p < 8; ++p) {
        int idx = p * 256 + tid;
        int row = m0 + (idx >> 4);
        if (row < M)
            *(short8*)(Cb + (size_t)row * 1152 + nl0 + (idx & 15) * 8) =
                *(const short8*)(smem + idx * 8);
    }
}

// ---------------------------------------------------------------------------
// Flash attention v3 (unchanged from round 7)
// ---------------------------------------------------------------------------
__global__ __launch_bounds__(256) void attn_flash3(
    const BF16* __restrict__ Q, const BF16* __restrict__ K,
    const BF16* __restrict__ VT, BF16* __restrict__ O)
{
    constexpr int NQ = 729, HDk = 96, DM = 1152, LDV = 768;
    __shared__ __align__(16) BF16 Ks[64 * 104];
    __shared__ __align__(16) BF16 Vs[112 * 64];
    __shared__ __align__(16) BF16 Ps[4][32 * 72];

    const int id = blockIdx.x;
    const int xcd = id & 7, slot = id >> 3;
    const int hb = slot / 6, qt = slot - hb * 6;
    const int hg = xcd * 12 + hb;
    const int b = hg / 12, hh = hg - b * 12;

    const int tid = threadIdx.x, wave = tid >> 6, lane = tid & 63;
    const int quad = lane >> 4, l16 = lane & 15;
    const size_t kbase = (size_t)b * (NQ * DM) + (size_t)hh * (NQ * HDk);
    const size_t vbase = (size_t)hg * 112 * LDV;

    const short8 zero8 = {0, 0, 0, 0, 0, 0, 0, 0};
    const v4f zf = {0.f, 0.f, 0.f, 0.f};
    const float C2 = 0.14724445f;   // (1/sqrt(96)) * log2(e)

    const int q0w = qt * 128 + wave * 32;
    short8 aq[2][3];
#pragma unroll
    for (int mt = 0; mt < 2; ++mt) {
        int qrow = q0w + mt * 16 + l16;
#pragma unroll
        for (int ks = 0; ks < 3; ++ks)
            aq[mt][ks] = (qrow < NQ)
                ? *(const short8*)(Q + kbase + (size_t)qrow * HDk + ks * 32 + quad * 8)
                : zero8;
    }

    int kk_[3], kg_[3];
#pragma unroll
    for (int i = 0; i < 3; ++i) {
        int c = tid + i * 256;
        kk_[i] = c / 12; kg_[i] = c - kk_[i] * 12;
    }
    int vq_[4], vgr_[4], vhd_[4];
#pragma unroll
    for (int i = 0; i < 4; ++i) {
        int q = wave + 4 * i;
        vq_[i] = q;
        int hd = q * 8 + (lane >> 3);
        vhd_[i] = hd;
        vgr_[i] = ((lane & 7) - hd) & 7;
    }

    v4f oacc[2][7];
#pragma unroll
    for (int mt = 0; mt < 2; ++mt)
#pragma unroll
        for (int nt = 0; nt < 7; ++nt) oacc[mt][nt] = zf;

    for (int kt = 0; kt < 12; ++kt) {
        const int k0 = kt * 64;
#pragma unroll
        for (int i = 0; i < 4; ++i) {
            if (vq_[i] < 14)
                async_cp16(VT + vbase + (size_t)vhd_[i] * LDV + k0 + vgr_[i] * 8,
                           Vs + vq_[i] * 512);
        }
#pragma unroll
        for (int i = 0; i < 3; ++i) {
            short8 v = *(const short8*)(K + kbase + (size_t)(k0 + kk_[i]) * HDk + kg_[i] * 8);
            *(short8*)(Ks + kk_[i] * 104 + kg_[i] * 8) = v;
        }
        __syncthreads();

        v4f s[2][4];
#pragma unroll
        for (int mt = 0; mt < 2; ++mt)
#pragma unroll
            for (int nt = 0; nt < 4; ++nt) s[mt][nt] = zf;
#pragma unroll
        for (int ks = 0; ks < 3; ++ks)
#pragma unroll
            for (int nt = 0; nt < 4; ++nt) {
                short8 bk = *(const short8*)(Ks + (nt * 16 + l16) * 104 + ks * 32 + quad * 8);
#pragma unroll
                for (int mt = 0; mt < 2; ++mt)
                    s[mt][nt] = __builtin_amdgcn_mfma_f32_16x16x32_bf16(
                        aq[mt][ks], bk, s[mt][nt], 0, 0, 0);
            }

        BF16* Pw = &Ps[wave][0];
#pragma unroll
        for (int mt = 0; mt < 2; ++mt)
#pragma unroll
            for (int nt = 0; nt < 4; ++nt)
#pragma unroll
                for (int r = 0; r < 4; ++r)
                    Pw[(mt * 16 + quad * 4 + r) * 72 + nt * 16 + l16] =
                        __float2bfloat16(exp2f(s[mt][nt][r] * C2));
        asm volatile("s_waitcnt lgkmcnt(0)" ::: "memory");

        short8 ap[2][2];
#pragma unroll
        for (int mt = 0; mt < 2; ++mt)
#pragma unroll
            for (int kc = 0; kc < 2; ++kc)
                ap[mt][kc] = *(const short8*)(Pw + (mt * 16 + l16) * 72 + kc * 32 + quad * 8);
#pragma unroll
        for (int nt = 0; nt < 7; ++nt) {
            int hd = nt * 16 + l16;
#pragma unroll
            for (int kc = 0; kc < 2; ++kc) {
                short8 bv = *(const short8*)(Vs + hd * 64 + (((kc * 4 + quad) + hd & 7) & 7) * 8);
#pragma unroll
                for (int mt = 0; mt < 2; ++mt)
                    oacc[mt][nt] = __builtin_amdgcn_mfma_f32_16x16x32_bf16(
                        ap[mt][kc], bv, oacc[mt][nt], 0, 0, 0);
            }
        }
        __syncthreads();
    }

#pragma unroll
    for (int mt = 0; mt < 2; ++mt) {
        const int qb = q0w + mt * 16 + quad * 4;
#pragma unroll
        for (int r = 0; r < 4; ++r) {
            int q = qb + r;
            float lv = __shfl(oacc[mt][6][r], quad << 4, 64);
            float inv = (lv > 0.f) ? 1.f / lv : 0.f;
            if (q >= NQ) continue;
#pragma unroll
            for (int nt = 0; nt < 6; ++nt)
                O[(size_t)b * (NQ * DM) + (size_t)q * DM + hh * HDk + nt * 16 + l16] =
                    __float2bfloat16(oacc[mt][nt][r] * inv);
        }
    }
}

// ---------------------------------------------------------------------------
// LayerNorm fused kernels (unchanged)
// ---------------------------------------------------------------------------
__device__ __forceinline__ float block_sum256(float v, float* red, int tid)
{
#pragma unroll
    for (int mm = 1; mm < 64; mm <<= 1) v += __shfl_xor(v, mm, 64);
    if ((tid & 63) == 0) red[tid >> 6] = v;
    __syncthreads();
    float r = red[0] + red[1] + red[2] + red[3];
    __syncthreads();
    return r;
}

__global__ __launch_bounds__(256) void ln1_gelu_kernel(
    const BF16* __restrict__ ao, const float* __restrict__ x,
    const float* __restrict__ gw, const float* __restrict__ bw,
    BF16* __restrict__ hout, BF16* __restrict__ gout)
{
    __shared__ float red[4];
    const int row = blockIdx.x, tid = threadIdx.x;
    const BF16* ar = ao + (size_t)row * 1152;
    float vals[5];
    float s = 0.f;
#pragma unroll
    for (int j = 0; j < 5; ++j) {
        int idx = tid + j * 256;
        vals[j] = (idx < 1152) ? __bfloat162float(ar[idx]) : 0.f;
        s += vals[j];
    }
    s = block_sum256(s, red, tid);
    float mu = s * (1.f / 1152.f);
    float vsum = 0.f;
#pragma unroll
    for (int j = 0; j < 5; ++j) {
        int idx = tid + j * 256;
        if (idx < 1152) { float d = vals[j] - mu; vsum += d * d; }
    }
    vsum = block_sum256(vsum, red, tid);
    float rstd = rsqrtf(vsum * (1.f / 1152.f) + 1e-6f);
#pragma unroll
    for (int j = 0; j < 5; ++j) {
        int idx = tid + j * 256;
        if (idx < 1152) {
            float hv = (vals[j] - mu) * rstd * gw[idx] + bw[idx]
                     + x[(size_t)row * 1152 + idx];
            hout[(size_t)row * 1152 + idx] = __float2bfloat16(hv);
            float t = hv;
            float gl = 0.5f * t * (1.f + tanhf(0.7978845608028654f * (t + 0.044715f * t * t * t)));
            gout[(size_t)row * 1152 + idx] = __float2bfloat16(gl);
        }
    }
}

__global__ __launch_bounds__(256) void ln2_kernel(
    const BF16* __restrict__ m2, const BF16* __restrict__ hf,
    const float* __restrict__ gw, const float* __restrict__ bw,
    float* __restrict__ out)
{
    __shared__ float red[4];
    const int row = blockIdx.x, tid = threadIdx.x;
    const BF16* mr = m2 + (size_t)row * 1152;
    float vals[5];
    float s = 0.f;
#pragma unroll
    for (int j = 0; j < 5; ++j) {
        int idx = tid + j * 256;
        vals[j] = (idx < 1152) ? __bfloat162float(mr[idx]) : 0.f;
        s += vals[j];
    }
    s = block_sum256(s, red, tid);
    float mu = s * (1.f / 1152.f);
    float vsum = 0.f;
#pragma unroll
    for (int j = 0; j < 5; ++j) {
        int idx = tid + j * 256;
        if (idx < 1152) { float d = vals[j] - mu; vsum += d * d; }
    }
    vsum = block_sum256(vsum, red, tid);
    float rstd = rsqrtf(vsum * (1.f / 1152.f) + 1e-6f);
#pragma unroll
    for (int j = 0; j < 5; ++j) {
        int idx = tid + j * 256;
        if (idx < 1152) {
            out[(size_t)row * 1152 + idx] =
                (vals[j] - mu) * rstd * gw[idx] + bw[idx]
              + __bfloat162float(hf[(size_t)row * 1152 + idx]);
        }
    }
}

// ---------------------------------------------------------------------------
// Workspace layout (~125 MB), same as round 7.
// ---------------------------------------------------------------------------
extern "C" void kernel_launch(void* const* d_in, const int* in_sizes, int n_in,
                              void* d_out, int out_size, void* d_ws, size_t ws_size,
                              hipStream_t stream)
{
    const float* x    = (const float*)d_in[0];
    const float* wq   = (const float*)d_in[1];
    const float* bq   = (const float*)d_in[2];
    const float* wk   = (const float*)d_in[3];
    const float* bk   = (const float*)d_in[4];
    const float* wv   = (const float*)d_in[5];
    const float* bv   = (const float*)d_in[6];
    const float* wo   = (const float*)d_in[7];
    const float* bo   = (const float*)d_in[8];
    const float* ln1g = (const float*)d_in[9];
    const float* ln1b = (const float*)d_in[10];
    const float* wfc1 = (const float*)d_in[11];
    const float* bfc1 = (const float*)d_in[12];
    const float* wfc2 = (const float*)d_in[13];
    const float* bfc2 = (const float*)d_in[14];
    const float* ln2g = (const float*)d_in[15];
    const float* ln2b = (const float*)d_in[16];

    const int T = 8 * 729;           // 5832
    const int D = 1152, HIDP = 4352;
    const size_t TD = (size_t)T * D;
    const size_t WDD = (size_t)D * D;

    BF16* wbq  = (BF16*)d_ws;                  // stacked QKV weights
    BF16* wbk  = wbq + WDD;
    BF16* wbv  = wbk + WDD;
    BF16* wbo  = wbv + WDD;
    BF16* wbf1 = wbo + WDD;
    BF16* wbf2 = wbf1 + (size_t)HIDP * D;
    BF16* xb   = wbf2 + (size_t)D * HIDP;
    BF16* S0   = xb + TD;
    BF16* S1   = S0 + TD;
    BF16* S2   = S1 + TD;
    BF16* S3   = S2 + TD;
    BF16* C0   = S3 + TD;
    BF16* C1   = C0 + TD;
    BF16* M1   = S0;                           // [T*4352] overlays S0..S3
    BF16* VT   = C0;                           // [96*112*768] overlays C0+C1 head

    dim3 blk(256);

    // one-shot converts
    const int n4_dd = (int)(WDD / 4);
    cvt4_kernel<<<(n4_dd + 255) / 256, blk, 0, stream>>>(wq, wbq, n4_dd, n4_dd);
    cvt4_kernel<<<(n4_dd + 255) / 256, blk, 0, stream>>>(wk, wbk, n4_dd, n4_dd);
    cvt4_kernel<<<(n4_dd + 255) / 256, blk, 0, stream>>>(wv, wbv, n4_dd, n4_dd);
    cvt4_kernel<<<(n4_dd + 255) / 256, blk, 0, stream>>>(wo, wbo, n4_dd, n4_dd);
    const int n4_f1s = 4304 * 1152 / 4, n4_f1d = HIDP * 1152 / 4;
    cvt4_kernel<<<(n4_f1d + 255) / 256, blk, 0, stream>>>(wfc1, wbf1, n4_f1s, n4_f1d);
    cvt_padcols_kernel<<<(1152 * 1088 + 255) / 256, blk, 0, stream>>>(wfc2, wbf2);
    const int n4_x = (int)(TD / 4);
    cvt4_kernel<<<(n4_x + 255) / 256, blk, 0, stream>>>(x, xb, n4_x, n4_x);

    // fused QKV projection: m fast (48 pad), n slow (27)
    gemm_qkv<<<dim3(48, 27), blk, 0, stream>>>(xb, wbq, bq, bk, bv, S0, TD, T);

    // V transpose (+ones row) + attention
    transpose_v3<<<dim3(96, 4), blk, 0, stream>>>(S2, VT);
    attn_flash3<<<576, blk, 0, stream>>>(S0, S1, VT, S3);

    // output projection
    gemm_bt_t<128><<<dim3(48, 9), blk, 0, stream>>>(S3, D, wbo, D, bo, D, C0, D, T, D);

    // LN1 + residual + gelu (gelu in-place over C0)
    ln1_gelu_kernel<<<T, blk, 0, stream>>>(C0, x, ln1g, ln1b, C1, C0);

    // MLP
    gemm_bt_t<128><<<dim3(48, 34), blk, 0, stream>>>(C0, D, wbf1, D, bfc1, 4304, M1, HIDP, T, D);
    gemm_bt_t<64><<<dim3(96, 9), blk, 0, stream>>>(M1, HIDP, wbf2, HIDP, bfc2, D, C0, D, T, HIDP);

    // LN2 + residual -> d_out (fp32)
    ln2_kernel<<<T, blk, 0, stream>>>(C0, C1, ln2g, ln2b, (float*)d_out);
}